// Round 14
// baseline (656.696 us; speedup 1.0000x reference)
//
#include <hip/hip_runtime.h>
#include <hip/hip_bf16.h>

typedef __hip_bfloat16 bf16;
typedef __attribute__((ext_vector_type(8))) short s16x8;
typedef __attribute__((ext_vector_type(4))) float f32x4;

__device__ __forceinline__ float u2f(unsigned short u){
  union { unsigned int i; float f; } v; v.i = ((unsigned int)u) << 16; return v.f;
}
__device__ __forceinline__ float bfu(bf16 x){ return __bfloat162float(x); }
__device__ __forceinline__ bf16  f2b(float x){ return __float2bfloat16(x); }

__device__ __forceinline__ void gload16(const void* g, void* l){
  __builtin_amdgcn_global_load_lds(
      (const __attribute__((address_space(1))) void*)g,
      (__attribute__((address_space(3))) void*)l, 16, 0, 0);
}

__device__ __forceinline__ float wave_sum(float v){
  #pragma unroll
  for (int o = 1; o < 64; o <<= 1) v += __shfl_xor(v, o, 64);
  return v;
}

__device__ __forceinline__ ushort4 cvt4(float4 v){
  ushort4 o;
  o.x = __bfloat16_as_ushort(f2b(v.x));
  o.y = __bfloat16_as_ushort(f2b(v.y));
  o.z = __bfloat16_as_ushort(f2b(v.z));
  o.w = __bfloat16_as_ushort(f2b(v.w));
  return o;
}
__device__ __forceinline__ float silu(float v){ return v / (1.f + __expf(-v)); }

// ---------------- prep + im2col in ONE dispatch (grid 4096) ----------------
__global__ __launch_bounds__(256) void prep_im2col_kernel(
    const float* __restrict__ x_flat,
    const float* __restrict__ caw, const float* __restrict__ cpw,
    const float* __restrict__ ipw, const float* __restrict__ opw,
    const float* __restrict__ xpw, const float* __restrict__ dtw,
    const float* __restrict__ alog,
    bf16* __restrict__ Aa, bf16* __restrict__ P,
    bf16* __restrict__ wa, bf16* __restrict__ wp,
    bf16* __restrict__ wbi, bf16* __restrict__ wbo,
    bf16* __restrict__ wxp, bf16* __restrict__ wdtp,
    float* __restrict__ atab)
{
  __shared__ float xs[512][8];
  const int tid = threadIdx.x;
  if (blockIdx.x < 2048){
    const int n = blockIdx.x;
    const float* xr = x_flat + (size_t)n * 3584;
    for (int i = tid; i < 3584; i += 256) xs[i / 7][i % 7] = xr[i];
    __syncthreads();
    bf16* Ar = Aa + (size_t)n * 4 * 1536;
    for (int i = tid; i < 6144; i += 256){
      int t = i / 1536, col = i - t*1536;
      int c = col / 3, kk = col - c*3;
      int p = 2*t - 1 + kk;
      float v = (p >= 0 && p < 7) ? xs[c][p] : 0.f;
      Ar[i] = f2b(v);
    }
    bf16* Pr = P + (size_t)n * 4 * 512;
    for (int i = tid; i < 2048; i += 256){
      int t = i >> 9, c = i & 511;
      int st = 2*t - 1;
      float m = -1e30f;
      #pragma unroll
      for (int k = 0; k < 3; ++k){ int p = st + k; if (p >= 0 && p < 7) m = fmaxf(m, xs[c][p]); }
      Pr[i] = f2b(m);
    }
  } else {
    for (int i = (blockIdx.x - 2048)*256 + tid; i < 1769472; i += 2048*256){
      if (i < 917504){
        int j = i;
        const float4* src; ushort4* dst;
        if (j < 98304)      { src = (const float4*)caw; dst = (ushort4*)wa; }
        else if (j < 131072){ j -= 98304;  src = (const float4*)cpw; dst = (ushort4*)wp; }
        else if (j < 655360){ j -= 131072; src = (const float4*)ipw; dst = (ushort4*)wbi; }
        else                { j -= 655360; src = (const float4*)opw; dst = (ushort4*)wbo; }
        dst[j] = cvt4(src[j]);
      } else if (i < 1441792){
        int idx = i - 917504;                 // xpw pad: [L][2*128][1024]
        int l = idx >> 18, rem = idx & 262143, row = rem >> 10, c = rem & 1023;
        int d = row >> 7, r = row & 127;
        float v = (r < 64) ? xpw[(((size_t)l*2 + d)*64 + r)*1024 + c] : 0.f;
        wxp[idx] = f2b(v);
      } else if (i < 1703936){
        int idx = i - 1441792;                // wdt pad: [4][1024][64]
        int ld = idx >> 16, rem = idx & 65535, r = rem >> 6, cc = rem & 63;
        float v = (cc < 32) ? dtw[((size_t)ld*1024 + r)*32 + cc] : 0.f;
        wdtp[idx] = f2b(v);
      } else {
        int idx = i - 1703936;                // atab (pre-scaled by log2 e)
        atab[idx] = -__expf(alog[idx]) * 1.44269504088896f;
      }
    }
  }
}

// ---------------- MFMA GEMM (BK=64): out = act(A·Wᵀ + bias) ---------------
template<int ACT, int OMODE, bool HASBIAS>
__global__ __launch_bounds__(256) void mgemm_kernel(
    const bf16* __restrict__ A, const bf16* __restrict__ W,
    const float* __restrict__ bias, void* __restrict__ outp,
    int K, int ldo)
{
  __shared__ char lsA[16384];
  __shared__ char lsB[16384];
  const int tid = threadIdx.x;
  const int w = tid >> 6, l = tid & 63;
  const int nwg = gridDim.x * gridDim.y;
  const int lin = blockIdx.y * gridDim.x + blockIdx.x;
  const int cpx = nwg >> 3;
  const int swz = (lin & 7) * cpx + (lin >> 3);
  const int m0 = (swz % gridDim.x) * 128, n0 = (swz / gridDim.x) * 128;
  const int wr = w >> 1, wc = w & 1;
  const size_t ldb = (size_t)K * 2;
  const char* Ab = (const char*)A + (size_t)m0 * ldb;
  const char* Wb = (const char*)W + (size_t)n0 * ldb;

  const int srow = l >> 3;
  const int scb  = ((l & 7) ^ srow) << 4;
  const int fr = l & 15;
  const int fg = l >> 4;
  const int fsw = (fr & 7) << 4;

  f32x4 acc[4][4];
  #pragma unroll
  for (int m = 0; m < 4; ++m)
    #pragma unroll
    for (int n = 0; n < 4; ++n) acc[m][n] = (f32x4){0.f,0.f,0.f,0.f};

  const int nk = K >> 6;
  for (int kt = 0; kt < nk; ++kt){
    const char* As = Ab + (size_t)kt * 128;
    const char* Ws = Wb + (size_t)kt * 128;
    #pragma unroll
    for (int i = 0; i < 4; ++i){
      int row = (i*4 + w)*8 + srow;
      gload16(As + (size_t)row*ldb + scb, &lsA[(i*4 + w)*1024]);
    }
    #pragma unroll
    for (int i = 0; i < 4; ++i){
      int row = (i*4 + w)*8 + srow;
      gload16(Ws + (size_t)row*ldb + scb, &lsB[(i*4 + w)*1024]);
    }
    __syncthreads();

    s16x8 af[4][2], bfr[4][2];
    #pragma unroll
    for (int m = 0; m < 4; ++m){
      int row = wr*64 + m*16 + fr;
      af[m][0] = *(const s16x8*)&lsA[row*128 + (( 0 + fg*16) ^ fsw)];
      af[m][1] = *(const s16x8*)&lsA[row*128 + ((64 + fg*16) ^ fsw)];
    }
    #pragma unroll
    for (int n = 0; n < 4; ++n){
      int row = wc*64 + n*16 + fr;
      bfr[n][0] = *(const s16x8*)&lsB[row*128 + (( 0 + fg*16) ^ fsw)];
      bfr[n][1] = *(const s16x8*)&lsB[row*128 + ((64 + fg*16) ^ fsw)];
    }
    #pragma unroll
    for (int m = 0; m < 4; ++m)
      #pragma unroll
      for (int n = 0; n < 4; ++n){
        acc[m][n] = __builtin_amdgcn_mfma_f32_16x16x32_bf16(af[m][0], bfr[n][0], acc[m][n], 0, 0, 0);
        acc[m][n] = __builtin_amdgcn_mfma_f32_16x16x32_bf16(af[m][1], bfr[n][1], acc[m][n], 0, 0, 0);
      }
    __syncthreads();
  }

  const int orow0 = m0 + wr*64, ocol0 = n0 + wc*64;
  #pragma unroll
  for (int n = 0; n < 4; ++n){
    int col = ocol0 + n*16 + fr;
    float bv = HASBIAS ? bias[col] : 0.f;
    #pragma unroll
    for (int m = 0; m < 4; ++m){
      int rbase = orow0 + m*16 + fg*4;
      #pragma unroll
      for (int r = 0; r < 4; ++r){
        float v = acc[m][n][r] + bv;
        if (ACT == 1) v = fmaxf(v, 0.f);
        if (ACT == 2) v = (v > 20.f) ? v : log1pf(__expf(v));
        size_t oi = (size_t)(rbase + r) * ldo + col;
        if (OMODE == 0)      ((bf16*)outp)[oi] = f2b(v);
        else if (OMODE == 1) ((float*)outp)[oi] = v;
        else                 ((float*)outp)[oi] += v;
      }
    }
  }
}

// ---------------- in_proj GEMM with fused dwconv+silu epilogue -------------
// K=512, grid (64,16). rows = n*4+t and rbase%4==0 => acc[m][n][r] holds the
// full time series (t=r) of one (sample,channel) per lane. For xi tiles
// (ocol<1024) compute both causal convs + silu in-register -> u[2]; never
// materialize xi. For z tiles write compact z[8192][1024].
__global__ __launch_bounds__(256) void ipgemm_kernel(
    const bf16* __restrict__ A, const bf16* __restrict__ W,
    const float* __restrict__ cw, const float* __restrict__ cb,
    bf16* __restrict__ u, bf16* __restrict__ z)
{
  __shared__ char lsA[16384];
  __shared__ char lsB[16384];
  const int tid = threadIdx.x;
  const int w = tid >> 6, l = tid & 63;
  const int nwg = gridDim.x * gridDim.y;
  const int lin = blockIdx.y * gridDim.x + blockIdx.x;
  const int cpx = nwg >> 3;
  const int swz = (lin & 7) * cpx + (lin >> 3);
  const int m0 = (swz % gridDim.x) * 128, n0 = (swz / gridDim.x) * 128;
  const int wr = w >> 1, wc = w & 1;
  const int K = 512;
  const size_t ldb = (size_t)K * 2;
  const char* Ab = (const char*)A + (size_t)m0 * ldb;
  const char* Wb = (const char*)W + (size_t)n0 * ldb;

  const int srow = l >> 3;
  const int scb  = ((l & 7) ^ srow) << 4;
  const int fr = l & 15;
  const int fg = l >> 4;
  const int fsw = (fr & 7) << 4;

  f32x4 acc[4][4];
  #pragma unroll
  for (int m = 0; m < 4; ++m)
    #pragma unroll
    for (int n = 0; n < 4; ++n) acc[m][n] = (f32x4){0.f,0.f,0.f,0.f};

  for (int kt = 0; kt < 8; ++kt){
    const char* As = Ab + (size_t)kt * 128;
    const char* Ws = Wb + (size_t)kt * 128;
    #pragma unroll
    for (int i = 0; i < 4; ++i){
      int row = (i*4 + w)*8 + srow;
      gload16(As + (size_t)row*ldb + scb, &lsA[(i*4 + w)*1024]);
    }
    #pragma unroll
    for (int i = 0; i < 4; ++i){
      int row = (i*4 + w)*8 + srow;
      gload16(Ws + (size_t)row*ldb + scb, &lsB[(i*4 + w)*1024]);
    }
    __syncthreads();

    s16x8 af[4][2], bfr[4][2];
    #pragma unroll
    for (int m = 0; m < 4; ++m){
      int row = wr*64 + m*16 + fr;
      af[m][0] = *(const s16x8*)&lsA[row*128 + (( 0 + fg*16) ^ fsw)];
      af[m][1] = *(const s16x8*)&lsA[row*128 + ((64 + fg*16) ^ fsw)];
    }
    #pragma unroll
    for (int n = 0; n < 4; ++n){
      int row = wc*64 + n*16 + fr;
      bfr[n][0] = *(const s16x8*)&lsB[row*128 + (( 0 + fg*16) ^ fsw)];
      bfr[n][1] = *(const s16x8*)&lsB[row*128 + ((64 + fg*16) ^ fsw)];
    }
    #pragma unroll
    for (int m = 0; m < 4; ++m)
      #pragma unroll
      for (int n = 0; n < 4; ++n){
        acc[m][n] = __builtin_amdgcn_mfma_f32_16x16x32_bf16(af[m][0], bfr[n][0], acc[m][n], 0, 0, 0);
        acc[m][n] = __builtin_amdgcn_mfma_f32_16x16x32_bf16(af[m][1], bfr[n][1], acc[m][n], 0, 0, 0);
      }
    __syncthreads();
  }

  const int orow0 = m0 + wr*64, ocol0 = n0 + wc*64;
  if (ocol0 < 1024){
    // xi half: fused causal conv (both dirs) + silu -> u
    #pragma unroll
    for (int n = 0; n < 4; ++n){
      int col = ocol0 + n*16 + fr;
      float4 w0 = *(const float4*)&cw[(size_t)col*4];          // dir 0
      float4 w1 = *(const float4*)&cw[4096 + (size_t)col*4];   // dir 1
      float b0 = cb[col], b1 = cb[1024 + col];
      #pragma unroll
      for (int m = 0; m < 4; ++m){
        int rbase = orow0 + m*16 + fg*4;     // 4-aligned: t = r
        float x0 = acc[m][n][0], x1 = acc[m][n][1];
        float x2 = acc[m][n][2], x3 = acc[m][n][3];
        float o0[4], o1[4];
        o0[0] = x0*w0.w + b0;
        o0[1] = x0*w0.z + x1*w0.w + b0;
        o0[2] = x0*w0.y + x1*w0.z + x2*w0.w + b0;
        o0[3] = x0*w0.x + x1*w0.y + x2*w0.z + x3*w0.w + b0;
        o1[0] = x3*w1.w + b1;
        o1[1] = x3*w1.z + x2*w1.w + b1;
        o1[2] = x3*w1.y + x2*w1.z + x1*w1.w + b1;
        o1[3] = x3*w1.x + x2*w1.y + x1*w1.z + x0*w1.w + b1;
        #pragma unroll
        for (int t = 0; t < 4; ++t){
          u[(size_t)(rbase + t)*1024 + col]           = f2b(silu(o0[t]));
          u[8388608 + (size_t)(rbase + t)*1024 + col] = f2b(silu(o1[t]));
        }
      }
    }
  } else {
    // z half: compact store
    #pragma unroll
    for (int n = 0; n < 4; ++n){
      int col = ocol0 - 1024 + n*16 + fr;
      #pragma unroll
      for (int m = 0; m < 4; ++m){
        int rbase = orow0 + m*16 + fg*4;
        #pragma unroll
        for (int r = 0; r < 4; ++r)
          z[(size_t)(rbase + r)*1024 + col] = f2b(acc[m][n][r]);
      }
    }
  }
}

// ---------------- batched stem GEMM: conv_a + conv_p in ONE dispatch -------
__global__ __launch_bounds__(256) void stemgemm_kernel(
    const bf16* __restrict__ Aa, const bf16* __restrict__ wa,
    const bf16* __restrict__ Pm, const bf16* __restrict__ wp,
    float* __restrict__ h)
{
  __shared__ char lsA[16384];
  __shared__ char lsB[16384];
  const int tid = threadIdx.x;
  const int w = tid >> 6, l = tid & 63;
  const int lin = blockIdx.y * gridDim.x + blockIdx.x;  // 256 blocks
  const int swz = (lin & 7) * 32 + (lin >> 3);
  const int tm = swz & 63, ty = swz >> 6;
  const int m0 = tm * 128;
  const bf16* A;
  const bf16* W;
  int K;
  if (ty < 2){ A = Aa; W = wa + (size_t)(ty)*128*1536; K = 1536; }
  else       { A = Pm; W = wp + (size_t)(ty-2)*128*512; K = 512; }
  const int wr = w >> 1, wc = w & 1;
  const size_t ldb = (size_t)K * 2;
  const char* Ab = (const char*)A + (size_t)m0 * ldb;
  const char* Wb = (const char*)W;

  const int srow = l >> 3;
  const int scb  = ((l & 7) ^ srow) << 4;
  const int fr = l & 15;
  const int fg = l >> 4;
  const int fsw = (fr & 7) << 4;

  f32x4 acc[4][4];
  #pragma unroll
  for (int m = 0; m < 4; ++m)
    #pragma unroll
    for (int n = 0; n < 4; ++n) acc[m][n] = (f32x4){0.f,0.f,0.f,0.f};

  const int nk = K >> 6;
  for (int kt = 0; kt < nk; ++kt){
    const char* As = Ab + (size_t)kt * 128;
    const char* Ws = Wb + (size_t)kt * 128;
    #pragma unroll
    for (int i = 0; i < 4; ++i){
      int row = (i*4 + w)*8 + srow;
      gload16(As + (size_t)row*ldb + scb, &lsA[(i*4 + w)*1024]);
    }
    #pragma unroll
    for (int i = 0; i < 4; ++i){
      int row = (i*4 + w)*8 + srow;
      gload16(Ws + (size_t)row*ldb + scb, &lsB[(i*4 + w)*1024]);
    }
    __syncthreads();

    s16x8 af[4][2], bfr[4][2];
    #pragma unroll
    for (int m = 0; m < 4; ++m){
      int row = wr*64 + m*16 + fr;
      af[m][0] = *(const s16x8*)&lsA[row*128 + (( 0 + fg*16) ^ fsw)];
      af[m][1] = *(const s16x8*)&lsA[row*128 + ((64 + fg*16) ^ fsw)];
    }
    #pragma unroll
    for (int n = 0; n < 4; ++n){
      int row = wc*64 + n*16 + fr;
      bfr[n][0] = *(const s16x8*)&lsB[row*128 + (( 0 + fg*16) ^ fsw)];
      bfr[n][1] = *(const s16x8*)&lsB[row*128 + ((64 + fg*16) ^ fsw)];
    }
    #pragma unroll
    for (int m = 0; m < 4; ++m)
      #pragma unroll
      for (int n = 0; n < 4; ++n){
        acc[m][n] = __builtin_amdgcn_mfma_f32_16x16x32_bf16(af[m][0], bfr[n][0], acc[m][n], 0, 0, 0);
        acc[m][n] = __builtin_amdgcn_mfma_f32_16x16x32_bf16(af[m][1], bfr[n][1], acc[m][n], 0, 0, 0);
      }
    __syncthreads();
  }

  const int orow0 = m0 + wr*64, ocol0 = ty*128 + wc*64;
  #pragma unroll
  for (int n = 0; n < 4; ++n){
    int col = ocol0 + n*16 + fr;
    #pragma unroll
    for (int m = 0; m < 4; ++m){
      int rbase = orow0 + m*16 + fg*4;
      #pragma unroll
      for (int r = 0; r < 4; ++r)
        h[(size_t)(rbase + r)*512 + col] = fmaxf(acc[m][n][r], 0.f);
    }
  }
}

// ---------------- MFMA GEMM (BK=128): half the barriers --------------------
template<int ACT, int OMODE, bool HASBIAS>
__global__ __launch_bounds__(256) void mgemm128_kernel(
    const bf16* __restrict__ A, const bf16* __restrict__ W,
    const float* __restrict__ bias, void* __restrict__ outp,
    int K, int ldo)
{
  __shared__ char lsA[32768];
  __shared__ char lsB[32768];
  const int tid = threadIdx.x;
  const int w = tid >> 6, l = tid & 63;
  const int nwg = gridDim.x * gridDim.y;
  const int lin = blockIdx.y * gridDim.x + blockIdx.x;
  const int cpx = nwg >> 3;
  const int swz = (lin & 7) * cpx + (lin >> 3);
  const int m0 = (swz % gridDim.x) * 128, n0 = (swz / gridDim.x) * 128;
  const int wr = w >> 1, wc = w & 1;
  const size_t ldb = (size_t)K * 2;
  const char* Ab = (const char*)A + (size_t)m0 * ldb;
  const char* Wb = (const char*)W + (size_t)n0 * ldb;

  const int srow4 = l >> 4;
  const int slot  = l & 15;
  const int fr = l & 15;
  const int fg = l >> 4;
  const int fx = fr & 7;

  f32x4 acc[4][4];
  #pragma unroll
  for (int m = 0; m < 4; ++m)
    #pragma unroll
    for (int n = 0; n < 4; ++n) acc[m][n] = (f32x4){0.f,0.f,0.f,0.f};

  const int nk = K >> 7;
  for (int kt = 0; kt < nk; ++kt){
    const char* As = Ab + (size_t)kt * 256;
    const char* Ws = Wb + (size_t)kt * 256;
    #pragma unroll
    for (int i = 0; i < 8; ++i){
      int c = i*4 + w;
      int row = c*4 + srow4;
      int colb = (slot ^ (row & 7)) << 4;
      gload16(As + (size_t)row*ldb + colb, &lsA[c*1024]);
      gload16(Ws + (size_t)row*ldb + colb, &lsB[c*1024]);
    }
    __syncthreads();

    #pragma unroll
    for (int half = 0; half < 2; ++half){
      s16x8 af[4][2], bfr[4][2];
      #pragma unroll
      for (int m = 0; m < 4; ++m){
        int row = wr*64 + m*16 + fr;
        af[m][0] = *(const s16x8*)&lsA[row*256 + ((((half*2+0)*4 + fg) ^ fx) << 4)];
        af[m][1] = *(const s16x8*)&lsA[row*256 + ((((half*2+1)*4 + fg) ^ fx) << 4)];
      }
      #pragma unroll
      for (int n = 0; n < 4; ++n){
        int row = wc*64 + n*16 + fr;
        bfr[n][0] = *(const s16x8*)&lsB[row*256 + ((((half*2+0)*4 + fg) ^ fx) << 4)];
        bfr[n][1] = *(const s16x8*)&lsB[row*256 + ((((half*2+1)*4 + fg) ^ fx) << 4)];
      }
      #pragma unroll
      for (int m = 0; m < 4; ++m)
        #pragma unroll
        for (int n = 0; n < 4; ++n){
          acc[m][n] = __builtin_amdgcn_mfma_f32_16x16x32_bf16(af[m][0], bfr[n][0], acc[m][n], 0, 0, 0);
          acc[m][n] = __builtin_amdgcn_mfma_f32_16x16x32_bf16(af[m][1], bfr[n][1], acc[m][n], 0, 0, 0);
        }
    }
    __syncthreads();
  }

  const int orow0 = m0 + wr*64, ocol0 = n0 + wc*64;
  #pragma unroll
  for (int n = 0; n < 4; ++n){
    int col = ocol0 + n*16 + fr;
    float bv = HASBIAS ? bias[col] : 0.f;
    #pragma unroll
    for (int m = 0; m < 4; ++m){
      int rbase = orow0 + m*16 + fg*4;
      #pragma unroll
      for (int r = 0; r < 4; ++r){
        float v = acc[m][n][r] + bv;
        if (ACT == 1) v = fmaxf(v, 0.f);
        if (ACT == 2) v = (v > 20.f) ? v : log1pf(__expf(v));
        size_t oi = (size_t)(rbase + r) * ldo + col;
        if (OMODE == 0)      ((bf16*)outp)[oi] = f2b(v);
        else if (OMODE == 1) ((float*)outp)[oi] = v;
        else                 ((float*)outp)[oi] += v;
      }
    }
  }
}

// ---------------- batched x_proj GEMM ---------------------------------------
__global__ __launch_bounds__(256) void bgemm_kernel(
    const bf16* __restrict__ A, const bf16* __restrict__ W,
    bf16* __restrict__ dtr_buf, float* __restrict__ dbl)
{
  __shared__ char lsA[16384];
  __shared__ char lsB[16384];
  const int tid = threadIdx.x;
  const int w = tid >> 6, l = tid & 63;
  const int nwg = gridDim.x * 2;
  const int lin = blockIdx.y * gridDim.x + blockIdx.x;
  const int cpx = nwg >> 3;
  const int swz = (lin & 7) * cpx + (lin >> 3);
  const int m0 = (swz % gridDim.x) * 128;
  const int d  = swz / gridDim.x;
  const int K = 1024;
  const int wr = w >> 1, wc = w & 1;
  const size_t ldb = (size_t)K * 2;
  const char* Ab = (const char*)(A + (size_t)d*8388608) + (size_t)m0 * ldb;
  const char* Wb = (const char*)(W + (size_t)d*131072);

  const int srow = l >> 3;
  const int scb  = ((l & 7) ^ srow) << 4;
  const int fr = l & 15;
  const int fg = l >> 4;
  const int fsw = (fr & 7) << 4;

  f32x4 acc[4][4];
  #pragma unroll
  for (int m = 0; m < 4; ++m)
    #pragma unroll
    for (int n = 0; n < 4; ++n) acc[m][n] = (f32x4){0.f,0.f,0.f,0.f};

  const int nk = K >> 6;
  for (int kt = 0; kt < nk; ++kt){
    const char* As = Ab + (size_t)kt * 128;
    const char* Ws = Wb + (size_t)kt * 128;
    #pragma unroll
    for (int i = 0; i < 4; ++i){
      int row = (i*4 + w)*8 + srow;
      gload16(As + (size_t)row*ldb + scb, &lsA[(i*4 + w)*1024]);
    }
    #pragma unroll
    for (int i = 0; i < 4; ++i){
      int row = (i*4 + w)*8 + srow;
      gload16(Ws + (size_t)row*ldb + scb, &lsB[(i*4 + w)*1024]);
    }
    __syncthreads();

    s16x8 af[4][2], bfr[4][2];
    #pragma unroll
    for (int m = 0; m < 4; ++m){
      int row = wr*64 + m*16 + fr;
      af[m][0] = *(const s16x8*)&lsA[row*128 + (( 0 + fg*16) ^ fsw)];
      af[m][1] = *(const s16x8*)&lsA[row*128 + ((64 + fg*16) ^ fsw)];
    }
    #pragma unroll
    for (int n = 0; n < 4; ++n){
      int row = wc*64 + n*16 + fr;
      bfr[n][0] = *(const s16x8*)&lsB[row*128 + (( 0 + fg*16) ^ fsw)];
      bfr[n][1] = *(const s16x8*)&lsB[row*128 + ((64 + fg*16) ^ fsw)];
    }
    #pragma unroll
    for (int m = 0; m < 4; ++m)
      #pragma unroll
      for (int n = 0; n < 4; ++n){
        acc[m][n] = __builtin_amdgcn_mfma_f32_16x16x32_bf16(af[m][0], bfr[n][0], acc[m][n], 0, 0, 0);
        acc[m][n] = __builtin_amdgcn_mfma_f32_16x16x32_bf16(af[m][1], bfr[n][1], acc[m][n], 0, 0, 0);
      }
    __syncthreads();
  }

  const int orow0 = m0 + wr*64, c0 = wc*64;
  #pragma unroll
  for (int n = 0; n < 4; ++n){
    int col = c0 + n*16 + fr;
    #pragma unroll
    for (int m = 0; m < 4; ++m){
      int rbase = orow0 + m*16 + fg*4;
      #pragma unroll
      for (int r = 0; r < 4; ++r){
        float v = acc[m][n][r];
        int row = rbase + r;
        if (col < 32)
          dtr_buf[((size_t)d*8192 + row)*64 + col] = f2b(v);
        else if (col < 64)
          dbl[(size_t)row*128 + d*64 + (col - 32)] = v;
        else if (col < 96)
          dtr_buf[((size_t)d*8192 + row)*64 + (col - 32)] = f2b(v);  // pad zeros
      }
    }
  }
}

// ---------------- dt_proj GEMM, both dirs in one dispatch ------------------
__global__ __launch_bounds__(256) void dtgemm_kernel(
    const bf16* __restrict__ A, const bf16* __restrict__ W2,
    const float* __restrict__ bias2, bf16* __restrict__ out2)
{
  __shared__ char lsA[16384];
  __shared__ char lsB[16384];
  const int tid = threadIdx.x;
  const int w = tid >> 6, l = tid & 63;
  const int nwg = gridDim.x * gridDim.y;          // 1024
  const int lin = blockIdx.y * gridDim.x + blockIdx.x;
  const int cpx = nwg >> 3;
  const int swz = (lin & 7) * cpx + (lin >> 3);
  const int m0 = (swz % gridDim.x) * 128, n0 = (swz / gridDim.x) * 128;
  const int d  = (m0 >= 8192) ? 1 : 0;
  const int wr = w >> 1, wc = w & 1;
  const size_t ldb = 128;
  const char* Ab = (const char*)A + (size_t)m0 * ldb;
  const char* Wb = (const char*)(W2 + (size_t)d*65536) + (size_t)n0 * ldb;
  const float* bias = bias2 + d*1024;
  bf16* outp = out2 + (size_t)d*8388608;

  const int srow = l >> 3;
  const int scb  = ((l & 7) ^ srow) << 4;
  const int fr = l & 15, fg = l >> 4;
  const int fsw = (fr & 7) << 4;

  f32x4 acc[4][4];
  #pragma unroll
  for (int m = 0; m < 4; ++m)
    #pragma unroll
    for (int n = 0; n < 4; ++n) acc[m][n] = (f32x4){0.f,0.f,0.f,0.f};

  #pragma unroll
  for (int i = 0; i < 4; ++i){
    int row = (i*4 + w)*8 + srow;
    gload16(Ab + (size_t)row*ldb + scb, &lsA[(i*4 + w)*1024]);
  }
  #pragma unroll
  for (int i = 0; i < 4; ++i){
    int row = (i*4 + w)*8 + srow;
    gload16(Wb + (size_t)row*ldb + scb, &lsB[(i*4 + w)*1024]);
  }
  __syncthreads();

  s16x8 af[4][2], bfr[4][2];
  #pragma unroll
  for (int m = 0; m < 4; ++m){
    int row = wr*64 + m*16 + fr;
    af[m][0] = *(const s16x8*)&lsA[row*128 + (( 0 + fg*16) ^ fsw)];
    af[m][1] = *(const s16x8*)&lsA[row*128 + ((64 + fg*16) ^ fsw)];
  }
  #pragma unroll
  for (int n = 0; n < 4; ++n){
    int row = wc*64 + n*16 + fr;
    bfr[n][0] = *(const s16x8*)&lsB[row*128 + (( 0 + fg*16) ^ fsw)];
    bfr[n][1] = *(const s16x8*)&lsB[row*128 + ((64 + fg*16) ^ fsw)];
  }
  #pragma unroll
  for (int m = 0; m < 4; ++m)
    #pragma unroll
    for (int n = 0; n < 4; ++n){
      acc[m][n] = __builtin_amdgcn_mfma_f32_16x16x32_bf16(af[m][0], bfr[n][0], acc[m][n], 0, 0, 0);
      acc[m][n] = __builtin_amdgcn_mfma_f32_16x16x32_bf16(af[m][1], bfr[n][1], acc[m][n], 0, 0, 0);
    }

  const int orow0 = (m0 - d*8192) + wr*64, ocol0 = n0 + wc*64;
  #pragma unroll
  for (int n = 0; n < 4; ++n){
    int col = ocol0 + n*16 + fr;
    float bv = bias[col];
    #pragma unroll
    for (int m = 0; m < 4; ++m){
      int rbase = orow0 + m*16 + fg*4;
      #pragma unroll
      for (int r = 0; r < 4; ++r){
        float v = acc[m][n][r] + bv;
        v = (v > 20.f) ? v : log1pf(__expf(v));          // softplus
        outp[(size_t)(rbase + r) * 1024 + col] = f2b(v);
      }
    }
  }
}

// ---------------- SE + layer-0 LN fused (one block per sample) -------------
__global__ __launch_bounds__(256) void se_ln_kernel(
    const float* __restrict__ sw1, const float* __restrict__ sb1,
    const float* __restrict__ sw2, const float* __restrict__ sb2,
    const float* __restrict__ g, const float* __restrict__ b,
    float* __restrict__ h, bf16* __restrict__ hn)
{
  __shared__ float yms[512];
  __shared__ float s1s[32];
  __shared__ float sg[512];
  const int n = blockIdx.x, tid = threadIdx.x;
  float* hb = h + (size_t)n * 2048;
  for (int c = tid; c < 512; c += 256)
    yms[c] = 0.25f * (hb[c] + hb[512+c] + hb[1024+c] + hb[1536+c]);
  __syncthreads();
  {
    int o = tid >> 3, sl = tid & 7;
    const float* wr = sw1 + (size_t)o * 512 + sl*64;
    const float* ym = yms + sl*64;
    float a = 0.f;
    #pragma unroll 16
    for (int i = 0; i < 64; ++i) a += wr[i] * ym[i];
    a += __shfl_down(a, 4, 8);
    a += __shfl_down(a, 2, 8);
    a += __shfl_down(a, 1, 8);
    if (sl == 0) s1s[o] = fmaxf(a + sb1[o], 0.f);
  }
  __syncthreads();
  for (int c = tid; c < 512; c += 256){
    float a = sb2[c];
    const float* wr = sw2 + (size_t)c * 32;
    #pragma unroll
    for (int j = 0; j < 32; ++j) a += wr[j] * s1s[j];
    sg[c] = 1.f / (1.f + __expf(-a));
  }
  __syncthreads();
  const int lane = tid & 63, wv = tid >> 6;
  float* hr = hb + wv*512;
  float4 v0 = ((float4*)hr)[lane], v1 = ((float4*)hr)[lane + 64];
  int c0 = lane*4, c1 = 256 + lane*4;
  v0.x *= sg[c0+0]; v0.y *= sg[c0+1]; v0.z *= sg[c0+2]; v0.w *= sg[c0+3];
  v1.x *= sg[c1+0]; v1.y *= sg[c1+1]; v1.z *= sg[c1+2]; v1.w *= sg[c1+3];
  ((float4*)hr)[lane] = v0;
  ((float4*)hr)[lane + 64] = v1;
  float s = wave_sum(v0.x+v0.y+v0.z+v0.w + v1.x+v1.y+v1.z+v1.w);
  float mu = s * (1.f/512.f);
  float d0x=v0.x-mu, d0y=v0.y-mu, d0z=v0.z-mu, d0w=v0.w-mu;
  float d1x=v1.x-mu, d1y=v1.y-mu, d1z=v1.z-mu, d1w=v1.w-mu;
  float sq = wave_sum(d0x*d0x+d0y*d0y+d0z*d0z+d0w*d0w +
                      d1x*d1x+d1y*d1y+d1z*d1z+d1w*d1w);
  float rstd = rsqrtf(sq * (1.f/512.f) + 1e-5f);
  float4 g0 = ((const float4*)g)[lane], g1 = ((const float4*)g)[lane+64];
  float4 b0 = ((const float4*)b)[lane], b1 = ((const float4*)b)[lane+64];
  ushort4 o0, o1;
  o0.x = __bfloat16_as_ushort(f2b(d0x*rstd*g0.x + b0.x));
  o0.y = __bfloat16_as_ushort(f2b(d0y*rstd*g0.y + b0.y));
  o0.z = __bfloat16_as_ushort(f2b(d0z*rstd*g0.z + b0.z));
  o0.w = __bfloat16_as_ushort(f2b(d0w*rstd*g0.w + b0.w));
  o1.x = __bfloat16_as_ushort(f2b(d1x*rstd*g1.x + b1.x));
  o1.y = __bfloat16_as_ushort(f2b(d1y*rstd*g1.y + b1.y));
  o1.z = __bfloat16_as_ushort(f2b(d1z*rstd*g1.z + b1.z));
  o1.w = __bfloat16_as_ushort(f2b(d1w*rstd*g1.w + b1.w));
  ushort4* orow = (ushort4*)(hn + ((size_t)n*4 + wv)*512);
  orow[lane] = o0;
  orow[lane + 64] = o1;
}

// ---------------- layernorm: wave-per-row, 4 rows/block, grid 2048 ---------
__global__ __launch_bounds__(256) void ln_kernel(
    const float* __restrict__ x, const float* __restrict__ g,
    const float* __restrict__ b, bf16* __restrict__ out)
{
  const int lane = threadIdx.x & 63, wid = threadIdx.x >> 6;
  const int row = blockIdx.x*4 + wid;
  const float4* xr = (const float4*)(x + (size_t)row*512);
  float4 v0 = xr[lane], v1 = xr[lane + 64];
  float s = wave_sum(v0.x+v0.y+v0.z+v0.w + v1.x+v1.y+v1.z+v1.w);
  float mu = s * (1.f/512.f);
  float d0x=v0.x-mu, d0y=v0.y-mu, d0z=v0.z-mu, d0w=v0.w-mu;
  float d1x=v1.x-mu, d1y=v1.y-mu, d1z=v1.z-mu, d1w=v1.w-mu;
  float sq = wave_sum(d0x*d0x+d0y*d0y+d0z*d0z+d0w*d0w +
                      d1x*d1x+d1y*d1y+d1z*d1z+d1w*d1w);
  float rstd = rsqrtf(sq * (1.f/512.f) + 1e-5f);
  float4 g0 = ((const float4*)g)[lane], g1 = ((const float4*)g)[lane+64];
  float4 b0 = ((const float4*)b)[lane], b1 = ((const float4*)b)[lane+64];
  ushort4 o0, o1;
  o0.x = __bfloat16_as_ushort(f2b(d0x*rstd*g0.x + b0.x));
  o0.y = __bfloat16_as_ushort(f2b(d0y*rstd*g0.y + b0.y));
  o0.z = __bfloat16_as_ushort(f2b(d0z*rstd*g0.z + b0.z));
  o0.w = __bfloat16_as_ushort(f2b(d0w*rstd*g0.w + b0.w));
  o1.x = __bfloat16_as_ushort(f2b(d1x*rstd*g1.x + b1.x));
  o1.y = __bfloat16_as_ushort(f2b(d1y*rstd*g1.y + b1.y));
  o1.z = __bfloat16_as_ushort(f2b(d1z*rstd*g1.z + b1.z));
  o1.w = __bfloat16_as_ushort(f2b(d1w*rstd*g1.w + b1.w));
  ushort4* orow = (ushort4*)(out + (size_t)row*512);
  orow[lane] = o0;
  orow[lane + 64] = o1;
}

// ---------------- final LN+mean (blocks 0..2047) + MLP weight conv ---------
__global__ __launch_bounds__(256) void finalln_mlp_kernel(
    const float* __restrict__ h, const float* __restrict__ g,
    const float* __restrict__ b, bf16* __restrict__ feat,
    const float4* __restrict__ w1, const float4* __restrict__ w2,
    ushort4* __restrict__ o1, ushort4* __restrict__ o2)
{
  __shared__ float red[4];
  const int tid = threadIdx.x;
  if (blockIdx.x < 2048){
    const int n = blockIdx.x, t = tid;
    float a0 = 0.f, a1 = 0.f;
    for (int tt = 0; tt < 4; ++tt){
      const float* xr = h + ((size_t)n*4 + tt)*512;
      float v0 = xr[t], v1 = xr[t+256];
      float sv = v0 + v1;
      #pragma unroll
      for (int o = 32; o > 0; o >>= 1) sv += __shfl_down(sv, o, 64);
      int lane = tid & 63, wid = tid >> 6;
      if (lane == 0) red[wid] = sv;
      __syncthreads();
      float s = red[0] + red[1] + red[2] + red[3];
      __syncthreads();
      float mu = s * (1.f/512.f);
      float d0 = v0 - mu, d1 = v1 - mu;
      float q = d0*d0 + d1*d1;
      #pragma unroll
      for (int o = 32; o > 0; o >>= 1) q += __shfl_down(q, o, 64);
      if (lane == 0) red[wid] = q;
      __syncthreads();
      float sq = red[0] + red[1] + red[2] + red[3];
      __syncthreads();
      float rstd = rsqrtf(sq * (1.f/512.f) + 1e-5f);
      a0 += d0*rstd*g[t]     + b[t];
      a1 += d1*rstd*g[t+256] + b[t+256];
    }
    feat[(size_t)n*512 + t]       = f2b(a0 * 0.25f);
    feat[(size_t)n*512 + t + 256] = f2b(a1 * 0.25f);
  } else {
    for (int i = (blockIdx.x - 2048)*256 + tid; i < 4718592; i += 4096*256){
      if (i < 524288) o1[i] = cvt4(w1[i]);
      else            o2[i - 524288] = cvt4(w2[i - 524288]);
    }
  }
}

// ---------------- fused bidirectional scan + gate --------------------------
// z is the compact [8192][1024] bf16 gate buffer.
__global__ __launch_bounds__(256) void scan2_kernel(
    const float* __restrict__ dbl, const bf16* __restrict__ dt2,
    const bf16* __restrict__ u, const bf16* __restrict__ z,
    const float* __restrict__ Atab2, const float* __restrict__ Dp,
    bf16* __restrict__ gated)
{
  __shared__ float Bs[2][4][16], Cs[2][4][16];
  const int n = blockIdx.x, g = blockIdx.y, tid = threadIdx.x;
  {
    int t = tid >> 6, j = tid & 63;
    int d = j >> 5, jj = j & 31;
    float v = dbl[((size_t)n*4 + t)*128 + d*64 + jj];
    if (jj < 16) Bs[d][t][jj] = v; else Cs[d][t][jj-16] = v;
  }
  __syncthreads();
  const int c = g*256 + tid;
  const size_t base = (size_t)n*4*1024 + c;
  float yo0[4], yo1[4];
  float hs[16];
  // ---- direction 0 ----
  {
    float A[16];
    const float4* ap = reinterpret_cast<const float4*>(Atab2 + (size_t)c*16);
    #pragma unroll
    for (int q = 0; q < 4; ++q){
      float4 v = ap[q];
      A[q*4+0]=v.x; A[q*4+1]=v.y; A[q*4+2]=v.z; A[q*4+3]=v.w;
    }
    const float Dpc = Dp[c];
    #pragma unroll
    for (int s = 0; s < 16; ++s) hs[s] = 0.f;
    #pragma unroll
    for (int t = 0; t < 4; ++t){
      float dtv = bfu(dt2[base + (size_t)t*1024]);
      float uv  = bfu(u  [base + (size_t)t*1024]);
      float du = dtv * uv;
      float yv = 0.f;
      #pragma unroll
      for (int s = 0; s < 16; ++s){
        float dA = __builtin_amdgcn_exp2f(dtv * A[s]);
        hs[s] = dA * hs[s] + du * Bs[0][t][s];
        yv += hs[s] * Cs[0][t][s];
      }
      yo0[t] = yv + uv * Dpc;
    }
  }
  // ---- direction 1 (time-reversed input; output flipped) ----
  {
    float A[16];
    const float4* ap = reinterpret_cast<const float4*>(Atab2 + 16384 + (size_t)c*16);
    #pragma unroll
    for (int q = 0; q < 4; ++q){
      float4 v = ap[q];
      A[q*4+0]=v.x; A[q*4+1]=v.y; A[q*4+2]=v.z; A[q*4+3]=v.w;
    }
    const float Dpc = Dp[1024 + c];
    #pragma unroll
    for (int s = 0; s < 16; ++s) hs[s] = 0.f;
    #pragma unroll
    for (int t = 0; t < 4; ++t){
      float dtv = bfu(dt2[8388608 + base + (size_t)t*1024]);
      float uv  = bfu(u  [8388608 + base + (size_t)t*1024]);
      float du = dtv * uv;
      float yv = 0.f;
      #pragma unroll
      for (int s = 0; s < 16; ++s){
        float dA = __builtin_amdgcn_exp2f(dtv * A[s]);
        hs[s] = dA * hs[s] + du * Bs[1][t][s];
        yv += hs[s] * Cs[1][t][s];
      }
      yo1[3 - t] = yv + uv * Dpc;
    }
  }
  // ---- gate + store ----
  #pragma unroll
  for (int t = 0; t < 4; ++t){
    float zv = bfu(z[base + (size_t)t*1024]);
    float sv = zv / (1.f + __expf(-zv));
    gated[base + (size_t)t*1024] = f2b((yo0[t] + yo1[t]) * sv);
  }
}

// ---------------- launch ---------------------------------------------------
extern "C" void kernel_launch(void* const* d_in, const int* in_sizes, int n_in,
                              void* d_out, int out_size, void* d_ws, size_t ws_size,
                              hipStream_t stream)
{
  const float* x_flat    = (const float*)d_in[0];
  const float* conv_a_w  = (const float*)d_in[1];
  const float* conv_p_w  = (const float*)d_in[2];
  const float* se_w1     = (const float*)d_in[3];
  const float* se_b1     = (const float*)d_in[4];
  const float* se_w2     = (const float*)d_in[5];
  const float* se_b2     = (const float*)d_in[6];
  const float* ln_g      = (const float*)d_in[7];
  const float* ln_b      = (const float*)d_in[8];
  const float* in_proj_w = (const float*)d_in[9];
  const float* conv_w    = (const float*)d_in[10];
  const float* conv_b    = (const float*)d_in[11];
  const float* x_proj_w  = (const float*)d_in[12];
  const float* dt_proj_w = (const float*)d_in[13];
  const float* dt_proj_b = (const float*)d_in[14];
  const float* A_log     = (const float*)d_in[15];
  const float* D_param   = (const float*)d_in[16];
  const float* out_proj_w= (const float*)d_in[17];
  const float* out_ln_g  = (const float*)d_in[18];
  const float* out_ln_b  = (const float*)d_in[19];
  const float* mlp_w1    = (const float*)d_in[20];
  const float* mlp_b1    = (const float*)d_in[21];
  const float* mlp_w2    = (const float*)d_in[22];
  const float* mlp_b2    = (const float*)d_in[23];

  char* ws = (char*)d_ws;
  const size_t OFF_H    = 0;                       // f32  8192*512  = 16.78MB
  const size_t OFF_HN   = OFF_H    + 16777216;     // bf16 8192*512  (feat overlay)
  const size_t OFF_XZ   = OFF_HN   + 8388608;      // bf16 z[8192][1024] (z1 overlay)
  const size_t OFF_U    = OFF_XZ   + 33554432;     // bf16 u[2] 8192*1024
  const size_t OFF_SCR  = OFF_U    + 33554432;     // Aa(stem)/dbl+dtrb(layers)/wb1(MLP)
  const size_t OFF_YB   = OFF_SCR  + 25165824;     // Pm+wa+wp(stem)/dt2(layers)/wb2(MLP)
  const size_t OFF_WB   = OFF_YB   + 33554432;     // bf16 in_proj+out_proj
  const size_t OFF_WXP  = OFF_WB   + 6291456;      // bf16 packed x_proj
  const size_t OFF_WDT  = OFF_WXP  + 1048576;      // bf16 padded dt_proj
  const size_t OFF_ATAB = OFF_WDT  + 524288;       // f32  4*1024*16

  float* h    = (float*)(ws + OFF_H);
  bf16*  hn   = (bf16*) (ws + OFF_HN);
  bf16*  z    = (bf16*) (ws + OFF_XZ);
  bf16*  u    = (bf16*) (ws + OFF_U);
  float* dbl  = (float*)(ws + OFF_SCR);
  bf16*  dtrb = (bf16*) (ws + OFF_SCR + 4194304);
  bf16*  dt2  = (bf16*) (ws + OFF_YB);
  bf16*  feat = (bf16*) (ws + OFF_HN);   // overlay
  bf16*  z1   = (bf16*) (ws + OFF_XZ);   // overlay (z dead by MLP time)
  bf16*  wbi  = (bf16*) (ws + OFF_WB);
  bf16*  wbo  = (bf16*) (ws + OFF_WB + 4194304);
  bf16*  wxp  = (bf16*) (ws + OFF_WXP);
  bf16*  wdtp = (bf16*) (ws + OFF_WDT);
  float* Atab = (float*)(ws + OFF_ATAB);
  bf16*  wb1  = (bf16*) (ws + OFF_SCR);  // overlay (MLP phase)
  bf16*  wb2  = (bf16*) (ws + OFF_YB);   // overlay (MLP phase)
  bf16*  Aa   = (bf16*) (ws + OFF_SCR);
  bf16*  Pm   = (bf16*) (ws + OFF_YB);
  bf16*  wa   = (bf16*) (ws + OFF_YB + 8388608);
  bf16*  wp   = (bf16*) (ws + OFF_YB + 8388608 + 786432);
  float* outf = (float*)d_out;

  prep_im2col_kernel<<<4096, 256, 0, stream>>>(
      x_flat, conv_a_w, conv_p_w, in_proj_w, out_proj_w, x_proj_w, dt_proj_w,
      A_log, Aa, Pm, wa, wp, wbi, wbo, wxp, wdtp, Atab);

  stemgemm_kernel<<<dim3(64,4), 256, 0, stream>>>(Aa, wa, Pm, wp, h);

  se_ln_kernel<<<2048, 256, 0, stream>>>(
      se_w1, se_b1, se_w2, se_b2, ln_g, ln_b, h, hn);

  for (int l = 0; l < 2; ++l){
    if (l == 1)
      ln_kernel<<<2048, 256, 0, stream>>>(h, ln_g + 512, ln_b + 512, hn);
    ipgemm_kernel<<<dim3(64,16), 256, 0, stream>>>(
        hn, wbi + (size_t)l*2048*512,
        conv_w + (size_t)l*8192, conv_b + (size_t)l*2048, u, z);
    bgemm_kernel<<<dim3(64,2), 256, 0, stream>>>(
        u, wxp + (size_t)l*262144, dtrb, dbl);
    dtgemm_kernel<<<dim3(128,8), 256, 0, stream>>>(
        dtrb, wdtp + (size_t)l*131072, dt_proj_b + (size_t)l*2048, dt2);
    scan2_kernel<<<dim3(2048,4), 256, 0, stream>>>(
        dbl, dt2, u, z, Atab + (size_t)l*32768, D_param + (size_t)l*2048,
        u /* gated overlays u dir0 */);
    mgemm128_kernel<0,2,false><<<dim3(64,4), 256, 0, stream>>>(
        u, wbo + (size_t)l*512*1024, nullptr, h, 1024, 512);
  }

  finalln_mlp_kernel<<<6144, 256, 0, stream>>>(
      h, out_ln_g, out_ln_b, feat,
      (const float4*)mlp_w1, (const float4*)mlp_w2, (ushort4*)wb1, (ushort4*)wb2);

  mgemm128_kernel<1,0,true><<<dim3(16,32), 256, 0, stream>>>(
      feat, wb1, mlp_b1, z1, 512, 4096);
  mgemm128_kernel<1,1,true><<<dim3(16,32), 256, 0, stream>>>(
      z1, wb2, mlp_b2, outf, 4096, 4096);
}

// Round 15
// 638.348 us; speedup vs baseline: 1.0287x; 1.0287x over previous
//
#include <hip/hip_runtime.h>
#include <hip/hip_bf16.h>

typedef __hip_bfloat16 bf16;
typedef __attribute__((ext_vector_type(8))) short s16x8;
typedef __attribute__((ext_vector_type(4))) float f32x4;

__device__ __forceinline__ float u2f(unsigned short u){
  union { unsigned int i; float f; } v; v.i = ((unsigned int)u) << 16; return v.f;
}
__device__ __forceinline__ float bfu(bf16 x){ return __bfloat162float(x); }
__device__ __forceinline__ bf16  f2b(float x){ return __float2bfloat16(x); }

__device__ __forceinline__ void gload16(const void* g, void* l){
  __builtin_amdgcn_global_load_lds(
      (const __attribute__((address_space(1))) void*)g,
      (__attribute__((address_space(3))) void*)l, 16, 0, 0);
}

__device__ __forceinline__ float wave_sum(float v){
  #pragma unroll
  for (int o = 1; o < 64; o <<= 1) v += __shfl_xor(v, o, 64);
  return v;
}

__device__ __forceinline__ ushort4 cvt4(float4 v){
  ushort4 o;
  o.x = __bfloat16_as_ushort(f2b(v.x));
  o.y = __bfloat16_as_ushort(f2b(v.y));
  o.z = __bfloat16_as_ushort(f2b(v.z));
  o.w = __bfloat16_as_ushort(f2b(v.w));
  return o;
}

// ---------------- prep + im2col in ONE dispatch (grid 4096) ----------------
__global__ __launch_bounds__(256) void prep_im2col_kernel(
    const float* __restrict__ x_flat,
    const float* __restrict__ caw, const float* __restrict__ cpw,
    const float* __restrict__ ipw, const float* __restrict__ opw,
    const float* __restrict__ xpw, const float* __restrict__ dtw,
    const float* __restrict__ alog,
    bf16* __restrict__ Aa, bf16* __restrict__ P,
    bf16* __restrict__ wa, bf16* __restrict__ wp,
    bf16* __restrict__ wbi, bf16* __restrict__ wbo,
    bf16* __restrict__ wxp, bf16* __restrict__ wdtp,
    float* __restrict__ atab)
{
  __shared__ float xs[512][8];
  const int tid = threadIdx.x;
  if (blockIdx.x < 2048){
    const int n = blockIdx.x;
    const float* xr = x_flat + (size_t)n * 3584;
    for (int i = tid; i < 3584; i += 256) xs[i / 7][i % 7] = xr[i];
    __syncthreads();
    bf16* Ar = Aa + (size_t)n * 4 * 1536;
    for (int i = tid; i < 6144; i += 256){
      int t = i / 1536, col = i - t*1536;
      int c = col / 3, kk = col - c*3;
      int p = 2*t - 1 + kk;
      float v = (p >= 0 && p < 7) ? xs[c][p] : 0.f;
      Ar[i] = f2b(v);
    }
    bf16* Pr = P + (size_t)n * 4 * 512;
    for (int i = tid; i < 2048; i += 256){
      int t = i >> 9, c = i & 511;
      int st = 2*t - 1;
      float m = -1e30f;
      #pragma unroll
      for (int k = 0; k < 3; ++k){ int p = st + k; if (p >= 0 && p < 7) m = fmaxf(m, xs[c][p]); }
      Pr[i] = f2b(m);
    }
  } else {
    for (int i = (blockIdx.x - 2048)*256 + tid; i < 1769472; i += 2048*256){
      if (i < 917504){
        int j = i;
        const float4* src; ushort4* dst;
        if (j < 98304)      { src = (const float4*)caw; dst = (ushort4*)wa; }
        else if (j < 131072){ j -= 98304;  src = (const float4*)cpw; dst = (ushort4*)wp; }
        else if (j < 655360){ j -= 131072; src = (const float4*)ipw; dst = (ushort4*)wbi; }
        else                { j -= 655360; src = (const float4*)opw; dst = (ushort4*)wbo; }
        dst[j] = cvt4(src[j]);
      } else if (i < 1441792){
        int idx = i - 917504;                 // xpw pad: [L][2*128][1024]
        int l = idx >> 18, rem = idx & 262143, row = rem >> 10, c = rem & 1023;
        int d = row >> 7, r = row & 127;
        float v = (r < 64) ? xpw[(((size_t)l*2 + d)*64 + r)*1024 + c] : 0.f;
        wxp[idx] = f2b(v);
      } else if (i < 1703936){
        int idx = i - 1441792;                // wdt pad: [4][1024][64]
        int ld = idx >> 16, rem = idx & 65535, r = rem >> 6, cc = rem & 63;
        float v = (cc < 32) ? dtw[((size_t)ld*1024 + r)*32 + cc] : 0.f;
        wdtp[idx] = f2b(v);
      } else {
        int idx = i - 1703936;                // atab (pre-scaled by log2 e)
        atab[idx] = -__expf(alog[idx]) * 1.44269504088896f;
      }
    }
  }
}

// ---------------- MFMA GEMM (BK=64): out = act(A·Wᵀ + bias) ---------------
template<int ACT, int OMODE, bool HASBIAS>
__global__ __launch_bounds__(256) void mgemm_kernel(
    const bf16* __restrict__ A, const bf16* __restrict__ W,
    const float* __restrict__ bias, void* __restrict__ outp,
    int K, int ldo)
{
  __shared__ char lsA[16384];
  __shared__ char lsB[16384];
  const int tid = threadIdx.x;
  const int w = tid >> 6, l = tid & 63;
  const int nwg = gridDim.x * gridDim.y;
  const int lin = blockIdx.y * gridDim.x + blockIdx.x;
  const int cpx = nwg >> 3;
  const int swz = (lin & 7) * cpx + (lin >> 3);
  const int m0 = (swz % gridDim.x) * 128, n0 = (swz / gridDim.x) * 128;
  const int wr = w >> 1, wc = w & 1;
  const size_t ldb = (size_t)K * 2;
  const char* Ab = (const char*)A + (size_t)m0 * ldb;
  const char* Wb = (const char*)W + (size_t)n0 * ldb;

  const int srow = l >> 3;
  const int scb  = ((l & 7) ^ srow) << 4;
  const int fr = l & 15;
  const int fg = l >> 4;
  const int fsw = (fr & 7) << 4;

  f32x4 acc[4][4];
  #pragma unroll
  for (int m = 0; m < 4; ++m)
    #pragma unroll
    for (int n = 0; n < 4; ++n) acc[m][n] = (f32x4){0.f,0.f,0.f,0.f};

  const int nk = K >> 6;
  for (int kt = 0; kt < nk; ++kt){
    const char* As = Ab + (size_t)kt * 128;
    const char* Ws = Wb + (size_t)kt * 128;
    #pragma unroll
    for (int i = 0; i < 4; ++i){
      int row = (i*4 + w)*8 + srow;
      gload16(As + (size_t)row*ldb + scb, &lsA[(i*4 + w)*1024]);
    }
    #pragma unroll
    for (int i = 0; i < 4; ++i){
      int row = (i*4 + w)*8 + srow;
      gload16(Ws + (size_t)row*ldb + scb, &lsB[(i*4 + w)*1024]);
    }
    __syncthreads();

    s16x8 af[4][2], bfr[4][2];
    #pragma unroll
    for (int m = 0; m < 4; ++m){
      int row = wr*64 + m*16 + fr;
      af[m][0] = *(const s16x8*)&lsA[row*128 + (( 0 + fg*16) ^ fsw)];
      af[m][1] = *(const s16x8*)&lsA[row*128 + ((64 + fg*16) ^ fsw)];
    }
    #pragma unroll
    for (int n = 0; n < 4; ++n){
      int row = wc*64 + n*16 + fr;
      bfr[n][0] = *(const s16x8*)&lsB[row*128 + (( 0 + fg*16) ^ fsw)];
      bfr[n][1] = *(const s16x8*)&lsB[row*128 + ((64 + fg*16) ^ fsw)];
    }
    #pragma unroll
    for (int m = 0; m < 4; ++m)
      #pragma unroll
      for (int n = 0; n < 4; ++n){
        acc[m][n] = __builtin_amdgcn_mfma_f32_16x16x32_bf16(af[m][0], bfr[n][0], acc[m][n], 0, 0, 0);
        acc[m][n] = __builtin_amdgcn_mfma_f32_16x16x32_bf16(af[m][1], bfr[n][1], acc[m][n], 0, 0, 0);
      }
    __syncthreads();
  }

  const int orow0 = m0 + wr*64, ocol0 = n0 + wc*64;
  #pragma unroll
  for (int n = 0; n < 4; ++n){
    int col = ocol0 + n*16 + fr;
    float bv = HASBIAS ? bias[col] : 0.f;
    #pragma unroll
    for (int m = 0; m < 4; ++m){
      int rbase = orow0 + m*16 + fg*4;
      #pragma unroll
      for (int r = 0; r < 4; ++r){
        float v = acc[m][n][r] + bv;
        if (ACT == 1) v = fmaxf(v, 0.f);
        if (ACT == 2) v = (v > 20.f) ? v : log1pf(__expf(v));
        size_t oi = (size_t)(rbase + r) * ldo + col;
        if (OMODE == 0)      ((bf16*)outp)[oi] = f2b(v);
        else if (OMODE == 1) ((float*)outp)[oi] = v;
        else                 ((float*)outp)[oi] += v;
      }
    }
  }
}

// ---------------- batched stem GEMM: conv_a + conv_p in ONE dispatch -------
__global__ __launch_bounds__(256) void stemgemm_kernel(
    const bf16* __restrict__ Aa, const bf16* __restrict__ wa,
    const bf16* __restrict__ Pm, const bf16* __restrict__ wp,
    float* __restrict__ h)
{
  __shared__ char lsA[16384];
  __shared__ char lsB[16384];
  const int tid = threadIdx.x;
  const int w = tid >> 6, l = tid & 63;
  const int lin = blockIdx.y * gridDim.x + blockIdx.x;  // 256 blocks
  const int swz = (lin & 7) * 32 + (lin >> 3);
  const int tm = swz & 63, ty = swz >> 6;
  const int m0 = tm * 128;
  const bf16* A;
  const bf16* W;
  int K;
  if (ty < 2){ A = Aa; W = wa + (size_t)(ty)*128*1536; K = 1536; }
  else       { A = Pm; W = wp + (size_t)(ty-2)*128*512; K = 512; }
  const int wr = w >> 1, wc = w & 1;
  const size_t ldb = (size_t)K * 2;
  const char* Ab = (const char*)A + (size_t)m0 * ldb;
  const char* Wb = (const char*)W;

  const int srow = l >> 3;
  const int scb  = ((l & 7) ^ srow) << 4;
  const int fr = l & 15;
  const int fg = l >> 4;
  const int fsw = (fr & 7) << 4;

  f32x4 acc[4][4];
  #pragma unroll
  for (int m = 0; m < 4; ++m)
    #pragma unroll
    for (int n = 0; n < 4; ++n) acc[m][n] = (f32x4){0.f,0.f,0.f,0.f};

  const int nk = K >> 6;
  for (int kt = 0; kt < nk; ++kt){
    const char* As = Ab + (size_t)kt * 128;
    const char* Ws = Wb + (size_t)kt * 128;
    #pragma unroll
    for (int i = 0; i < 4; ++i){
      int row = (i*4 + w)*8 + srow;
      gload16(As + (size_t)row*ldb + scb, &lsA[(i*4 + w)*1024]);
    }
    #pragma unroll
    for (int i = 0; i < 4; ++i){
      int row = (i*4 + w)*8 + srow;
      gload16(Ws + (size_t)row*ldb + scb, &lsB[(i*4 + w)*1024]);
    }
    __syncthreads();

    s16x8 af[4][2], bfr[4][2];
    #pragma unroll
    for (int m = 0; m < 4; ++m){
      int row = wr*64 + m*16 + fr;
      af[m][0] = *(const s16x8*)&lsA[row*128 + (( 0 + fg*16) ^ fsw)];
      af[m][1] = *(const s16x8*)&lsA[row*128 + ((64 + fg*16) ^ fsw)];
    }
    #pragma unroll
    for (int n = 0; n < 4; ++n){
      int row = wc*64 + n*16 + fr;
      bfr[n][0] = *(const s16x8*)&lsB[row*128 + (( 0 + fg*16) ^ fsw)];
      bfr[n][1] = *(const s16x8*)&lsB[row*128 + ((64 + fg*16) ^ fsw)];
    }
    #pragma unroll
    for (int m = 0; m < 4; ++m)
      #pragma unroll
      for (int n = 0; n < 4; ++n){
        acc[m][n] = __builtin_amdgcn_mfma_f32_16x16x32_bf16(af[m][0], bfr[n][0], acc[m][n], 0, 0, 0);
        acc[m][n] = __builtin_amdgcn_mfma_f32_16x16x32_bf16(af[m][1], bfr[n][1], acc[m][n], 0, 0, 0);
      }
    __syncthreads();
  }

  const int orow0 = m0 + wr*64, ocol0 = ty*128 + wc*64;
  #pragma unroll
  for (int n = 0; n < 4; ++n){
    int col = ocol0 + n*16 + fr;
    #pragma unroll
    for (int m = 0; m < 4; ++m){
      int rbase = orow0 + m*16 + fg*4;
      #pragma unroll
      for (int r = 0; r < 4; ++r)
        h[(size_t)(rbase + r)*512 + col] = fmaxf(acc[m][n][r], 0.f);
    }
  }
}

// ---------------- MFMA GEMM (BK=128): half the barriers --------------------
template<int ACT, int OMODE, bool HASBIAS>
__global__ __launch_bounds__(256) void mgemm128_kernel(
    const bf16* __restrict__ A, const bf16* __restrict__ W,
    const float* __restrict__ bias, void* __restrict__ outp,
    int K, int ldo)
{
  __shared__ char lsA[32768];
  __shared__ char lsB[32768];
  const int tid = threadIdx.x;
  const int w = tid >> 6, l = tid & 63;
  const int nwg = gridDim.x * gridDim.y;
  const int lin = blockIdx.y * gridDim.x + blockIdx.x;
  const int cpx = nwg >> 3;
  const int swz = (lin & 7) * cpx + (lin >> 3);
  const int m0 = (swz % gridDim.x) * 128, n0 = (swz / gridDim.x) * 128;
  const int wr = w >> 1, wc = w & 1;
  const size_t ldb = (size_t)K * 2;
  const char* Ab = (const char*)A + (size_t)m0 * ldb;
  const char* Wb = (const char*)W + (size_t)n0 * ldb;

  const int srow4 = l >> 4;
  const int slot  = l & 15;
  const int fr = l & 15;
  const int fg = l >> 4;
  const int fx = fr & 7;

  f32x4 acc[4][4];
  #pragma unroll
  for (int m = 0; m < 4; ++m)
    #pragma unroll
    for (int n = 0; n < 4; ++n) acc[m][n] = (f32x4){0.f,0.f,0.f,0.f};

  const int nk = K >> 7;
  for (int kt = 0; kt < nk; ++kt){
    const char* As = Ab + (size_t)kt * 256;
    const char* Ws = Wb + (size_t)kt * 256;
    #pragma unroll
    for (int i = 0; i < 8; ++i){
      int c = i*4 + w;
      int row = c*4 + srow4;
      int colb = (slot ^ (row & 7)) << 4;
      gload16(As + (size_t)row*ldb + colb, &lsA[c*1024]);
      gload16(Ws + (size_t)row*ldb + colb, &lsB[c*1024]);
    }
    __syncthreads();

    #pragma unroll
    for (int half = 0; half < 2; ++half){
      s16x8 af[4][2], bfr[4][2];
      #pragma unroll
      for (int m = 0; m < 4; ++m){
        int row = wr*64 + m*16 + fr;
        af[m][0] = *(const s16x8*)&lsA[row*256 + ((((half*2+0)*4 + fg) ^ fx) << 4)];
        af[m][1] = *(const s16x8*)&lsA[row*256 + ((((half*2+1)*4 + fg) ^ fx) << 4)];
      }
      #pragma unroll
      for (int n = 0; n < 4; ++n){
        int row = wc*64 + n*16 + fr;
        bfr[n][0] = *(const s16x8*)&lsB[row*256 + ((((half*2+0)*4 + fg) ^ fx) << 4)];
        bfr[n][1] = *(const s16x8*)&lsB[row*256 + ((((half*2+1)*4 + fg) ^ fx) << 4)];
      }
      #pragma unroll
      for (int m = 0; m < 4; ++m)
        #pragma unroll
        for (int n = 0; n < 4; ++n){
          acc[m][n] = __builtin_amdgcn_mfma_f32_16x16x32_bf16(af[m][0], bfr[n][0], acc[m][n], 0, 0, 0);
          acc[m][n] = __builtin_amdgcn_mfma_f32_16x16x32_bf16(af[m][1], bfr[n][1], acc[m][n], 0, 0, 0);
        }
    }
    __syncthreads();
  }

  const int orow0 = m0 + wr*64, ocol0 = n0 + wc*64;
  #pragma unroll
  for (int n = 0; n < 4; ++n){
    int col = ocol0 + n*16 + fr;
    float bv = HASBIAS ? bias[col] : 0.f;
    #pragma unroll
    for (int m = 0; m < 4; ++m){
      int rbase = orow0 + m*16 + fg*4;
      #pragma unroll
      for (int r = 0; r < 4; ++r){
        float v = acc[m][n][r] + bv;
        if (ACT == 1) v = fmaxf(v, 0.f);
        if (ACT == 2) v = (v > 20.f) ? v : log1pf(__expf(v));
        size_t oi = (size_t)(rbase + r) * ldo + col;
        if (OMODE == 0)      ((bf16*)outp)[oi] = f2b(v);
        else if (OMODE == 1) ((float*)outp)[oi] = v;
        else                 ((float*)outp)[oi] += v;
      }
    }
  }
}

// ---------------- batched x_proj GEMM ---------------------------------------
__global__ __launch_bounds__(256) void bgemm_kernel(
    const bf16* __restrict__ A, const bf16* __restrict__ W,
    bf16* __restrict__ dtr_buf, float* __restrict__ dbl)
{
  __shared__ char lsA[16384];
  __shared__ char lsB[16384];
  const int tid = threadIdx.x;
  const int w = tid >> 6, l = tid & 63;
  const int nwg = gridDim.x * 2;
  const int lin = blockIdx.y * gridDim.x + blockIdx.x;
  const int cpx = nwg >> 3;
  const int swz = (lin & 7) * cpx + (lin >> 3);
  const int m0 = (swz % gridDim.x) * 128;
  const int d  = swz / gridDim.x;
  const int K = 1024;
  const int wr = w >> 1, wc = w & 1;
  const size_t ldb = (size_t)K * 2;
  const char* Ab = (const char*)(A + (size_t)d*8388608) + (size_t)m0 * ldb;
  const char* Wb = (const char*)(W + (size_t)d*131072);

  const int srow = l >> 3;
  const int scb  = ((l & 7) ^ srow) << 4;
  const int fr = l & 15;
  const int fg = l >> 4;
  const int fsw = (fr & 7) << 4;

  f32x4 acc[4][4];
  #pragma unroll
  for (int m = 0; m < 4; ++m)
    #pragma unroll
    for (int n = 0; n < 4; ++n) acc[m][n] = (f32x4){0.f,0.f,0.f,0.f};

  const int nk = K >> 6;
  for (int kt = 0; kt < nk; ++kt){
    const char* As = Ab + (size_t)kt * 128;
    const char* Ws = Wb + (size_t)kt * 128;
    #pragma unroll
    for (int i = 0; i < 4; ++i){
      int row = (i*4 + w)*8 + srow;
      gload16(As + (size_t)row*ldb + scb, &lsA[(i*4 + w)*1024]);
    }
    #pragma unroll
    for (int i = 0; i < 4; ++i){
      int row = (i*4 + w)*8 + srow;
      gload16(Ws + (size_t)row*ldb + scb, &lsB[(i*4 + w)*1024]);
    }
    __syncthreads();

    s16x8 af[4][2], bfr[4][2];
    #pragma unroll
    for (int m = 0; m < 4; ++m){
      int row = wr*64 + m*16 + fr;
      af[m][0] = *(const s16x8*)&lsA[row*128 + (( 0 + fg*16) ^ fsw)];
      af[m][1] = *(const s16x8*)&lsA[row*128 + ((64 + fg*16) ^ fsw)];
    }
    #pragma unroll
    for (int n = 0; n < 4; ++n){
      int row = wc*64 + n*16 + fr;
      bfr[n][0] = *(const s16x8*)&lsB[row*128 + (( 0 + fg*16) ^ fsw)];
      bfr[n][1] = *(const s16x8*)&lsB[row*128 + ((64 + fg*16) ^ fsw)];
    }
    #pragma unroll
    for (int m = 0; m < 4; ++m)
      #pragma unroll
      for (int n = 0; n < 4; ++n){
        acc[m][n] = __builtin_amdgcn_mfma_f32_16x16x32_bf16(af[m][0], bfr[n][0], acc[m][n], 0, 0, 0);
        acc[m][n] = __builtin_amdgcn_mfma_f32_16x16x32_bf16(af[m][1], bfr[n][1], acc[m][n], 0, 0, 0);
      }
    __syncthreads();
  }

  const int orow0 = m0 + wr*64, c0 = wc*64;
  #pragma unroll
  for (int n = 0; n < 4; ++n){
    int col = c0 + n*16 + fr;
    #pragma unroll
    for (int m = 0; m < 4; ++m){
      int rbase = orow0 + m*16 + fg*4;
      #pragma unroll
      for (int r = 0; r < 4; ++r){
        float v = acc[m][n][r];
        int row = rbase + r;
        if (col < 32)
          dtr_buf[((size_t)d*8192 + row)*64 + col] = f2b(v);
        else if (col < 64)
          dbl[(size_t)row*128 + d*64 + (col - 32)] = v;
        else if (col < 96)
          dtr_buf[((size_t)d*8192 + row)*64 + (col - 32)] = f2b(v);  // pad zeros
      }
    }
  }
}

// ---------------- dt_proj GEMM, both dirs in one dispatch ------------------
__global__ __launch_bounds__(256) void dtgemm_kernel(
    const bf16* __restrict__ A, const bf16* __restrict__ W2,
    const float* __restrict__ bias2, bf16* __restrict__ out2)
{
  __shared__ char lsA[16384];
  __shared__ char lsB[16384];
  const int tid = threadIdx.x;
  const int w = tid >> 6, l = tid & 63;
  const int nwg = gridDim.x * gridDim.y;          // 1024
  const int lin = blockIdx.y * gridDim.x + blockIdx.x;
  const int cpx = nwg >> 3;
  const int swz = (lin & 7) * cpx + (lin >> 3);
  const int m0 = (swz % gridDim.x) * 128, n0 = (swz / gridDim.x) * 128;
  const int d  = (m0 >= 8192) ? 1 : 0;
  const int wr = w >> 1, wc = w & 1;
  const size_t ldb = 128;
  const char* Ab = (const char*)A + (size_t)m0 * ldb;
  const char* Wb = (const char*)(W2 + (size_t)d*65536) + (size_t)n0 * ldb;
  const float* bias = bias2 + d*1024;
  bf16* outp = out2 + (size_t)d*8388608;

  const int srow = l >> 3;
  const int scb  = ((l & 7) ^ srow) << 4;
  const int fr = l & 15, fg = l >> 4;
  const int fsw = (fr & 7) << 4;

  f32x4 acc[4][4];
  #pragma unroll
  for (int m = 0; m < 4; ++m)
    #pragma unroll
    for (int n = 0; n < 4; ++n) acc[m][n] = (f32x4){0.f,0.f,0.f,0.f};

  #pragma unroll
  for (int i = 0; i < 4; ++i){
    int row = (i*4 + w)*8 + srow;
    gload16(Ab + (size_t)row*ldb + scb, &lsA[(i*4 + w)*1024]);
  }
  #pragma unroll
  for (int i = 0; i < 4; ++i){
    int row = (i*4 + w)*8 + srow;
    gload16(Wb + (size_t)row*ldb + scb, &lsB[(i*4 + w)*1024]);
  }
  __syncthreads();

  s16x8 af[4][2], bfr[4][2];
  #pragma unroll
  for (int m = 0; m < 4; ++m){
    int row = wr*64 + m*16 + fr;
    af[m][0] = *(const s16x8*)&lsA[row*128 + (( 0 + fg*16) ^ fsw)];
    af[m][1] = *(const s16x8*)&lsA[row*128 + ((64 + fg*16) ^ fsw)];
  }
  #pragma unroll
  for (int n = 0; n < 4; ++n){
    int row = wc*64 + n*16 + fr;
    bfr[n][0] = *(const s16x8*)&lsB[row*128 + (( 0 + fg*16) ^ fsw)];
    bfr[n][1] = *(const s16x8*)&lsB[row*128 + ((64 + fg*16) ^ fsw)];
  }
  #pragma unroll
  for (int m = 0; m < 4; ++m)
    #pragma unroll
    for (int n = 0; n < 4; ++n){
      acc[m][n] = __builtin_amdgcn_mfma_f32_16x16x32_bf16(af[m][0], bfr[n][0], acc[m][n], 0, 0, 0);
      acc[m][n] = __builtin_amdgcn_mfma_f32_16x16x32_bf16(af[m][1], bfr[n][1], acc[m][n], 0, 0, 0);
    }

  const int orow0 = (m0 - d*8192) + wr*64, ocol0 = n0 + wc*64;
  #pragma unroll
  for (int n = 0; n < 4; ++n){
    int col = ocol0 + n*16 + fr;
    float bv = bias[col];
    #pragma unroll
    for (int m = 0; m < 4; ++m){
      int rbase = orow0 + m*16 + fg*4;
      #pragma unroll
      for (int r = 0; r < 4; ++r){
        float v = acc[m][n][r] + bv;
        v = (v > 20.f) ? v : log1pf(__expf(v));          // softplus
        outp[(size_t)(rbase + r) * 1024 + col] = f2b(v);
      }
    }
  }
}

// ---------------- SE + layer-0 LN fused (one block per sample) -------------
__global__ __launch_bounds__(256) void se_ln_kernel(
    const float* __restrict__ sw1, const float* __restrict__ sb1,
    const float* __restrict__ sw2, const float* __restrict__ sb2,
    const float* __restrict__ g, const float* __restrict__ b,
    float* __restrict__ h, bf16* __restrict__ hn)
{
  __shared__ float yms[512];
  __shared__ float s1s[32];
  __shared__ float sg[512];
  const int n = blockIdx.x, tid = threadIdx.x;
  float* hb = h + (size_t)n * 2048;
  for (int c = tid; c < 512; c += 256)
    yms[c] = 0.25f * (hb[c] + hb[512+c] + hb[1024+c] + hb[1536+c]);
  __syncthreads();
  {
    int o = tid >> 3, sl = tid & 7;
    const float* wr = sw1 + (size_t)o * 512 + sl*64;
    const float* ym = yms + sl*64;
    float a = 0.f;
    #pragma unroll 16
    for (int i = 0; i < 64; ++i) a += wr[i] * ym[i];
    a += __shfl_down(a, 4, 8);
    a += __shfl_down(a, 2, 8);
    a += __shfl_down(a, 1, 8);
    if (sl == 0) s1s[o] = fmaxf(a + sb1[o], 0.f);
  }
  __syncthreads();
  for (int c = tid; c < 512; c += 256){
    float a = sb2[c];
    const float* wr = sw2 + (size_t)c * 32;
    #pragma unroll
    for (int j = 0; j < 32; ++j) a += wr[j] * s1s[j];
    sg[c] = 1.f / (1.f + __expf(-a));
  }
  __syncthreads();
  const int lane = tid & 63, wv = tid >> 6;
  float* hr = hb + wv*512;
  float4 v0 = ((float4*)hr)[lane], v1 = ((float4*)hr)[lane + 64];
  int c0 = lane*4, c1 = 256 + lane*4;
  v0.x *= sg[c0+0]; v0.y *= sg[c0+1]; v0.z *= sg[c0+2]; v0.w *= sg[c0+3];
  v1.x *= sg[c1+0]; v1.y *= sg[c1+1]; v1.z *= sg[c1+2]; v1.w *= sg[c1+3];
  ((float4*)hr)[lane] = v0;
  ((float4*)hr)[lane + 64] = v1;
  float s = wave_sum(v0.x+v0.y+v0.z+v0.w + v1.x+v1.y+v1.z+v1.w);
  float mu = s * (1.f/512.f);
  float d0x=v0.x-mu, d0y=v0.y-mu, d0z=v0.z-mu, d0w=v0.w-mu;
  float d1x=v1.x-mu, d1y=v1.y-mu, d1z=v1.z-mu, d1w=v1.w-mu;
  float sq = wave_sum(d0x*d0x+d0y*d0y+d0z*d0z+d0w*d0w +
                      d1x*d1x+d1y*d1y+d1z*d1z+d1w*d1w);
  float rstd = rsqrtf(sq * (1.f/512.f) + 1e-5f);
  float4 g0 = ((const float4*)g)[lane], g1 = ((const float4*)g)[lane+64];
  float4 b0 = ((const float4*)b)[lane], b1 = ((const float4*)b)[lane+64];
  ushort4 o0, o1;
  o0.x = __bfloat16_as_ushort(f2b(d0x*rstd*g0.x + b0.x));
  o0.y = __bfloat16_as_ushort(f2b(d0y*rstd*g0.y + b0.y));
  o0.z = __bfloat16_as_ushort(f2b(d0z*rstd*g0.z + b0.z));
  o0.w = __bfloat16_as_ushort(f2b(d0w*rstd*g0.w + b0.w));
  o1.x = __bfloat16_as_ushort(f2b(d1x*rstd*g1.x + b1.x));
  o1.y = __bfloat16_as_ushort(f2b(d1y*rstd*g1.y + b1.y));
  o1.z = __bfloat16_as_ushort(f2b(d1z*rstd*g1.z + b1.z));
  o1.w = __bfloat16_as_ushort(f2b(d1w*rstd*g1.w + b1.w));
  ushort4* orow = (ushort4*)(hn + ((size_t)n*4 + wv)*512);
  orow[lane] = o0;
  orow[lane + 64] = o1;
}

// ---------------- layernorm: wave-per-row, 4 rows/block, grid 2048 ---------
__global__ __launch_bounds__(256) void ln_kernel(
    const float* __restrict__ x, const float* __restrict__ g,
    const float* __restrict__ b, bf16* __restrict__ out)
{
  const int lane = threadIdx.x & 63, wid = threadIdx.x >> 6;
  const int row = blockIdx.x*4 + wid;
  const float4* xr = (const float4*)(x + (size_t)row*512);
  float4 v0 = xr[lane], v1 = xr[lane + 64];
  float s = wave_sum(v0.x+v0.y+v0.z+v0.w + v1.x+v1.y+v1.z+v1.w);
  float mu = s * (1.f/512.f);
  float d0x=v0.x-mu, d0y=v0.y-mu, d0z=v0.z-mu, d0w=v0.w-mu;
  float d1x=v1.x-mu, d1y=v1.y-mu, d1z=v1.z-mu, d1w=v1.w-mu;
  float sq = wave_sum(d0x*d0x+d0y*d0y+d0z*d0z+d0w*d0w +
                      d1x*d1x+d1y*d1y+d1z*d1z+d1w*d1w);
  float rstd = rsqrtf(sq * (1.f/512.f) + 1e-5f);
  float4 g0 = ((const float4*)g)[lane], g1 = ((const float4*)g)[lane+64];
  float4 b0 = ((const float4*)b)[lane], b1 = ((const float4*)b)[lane+64];
  ushort4 o0, o1;
  o0.x = __bfloat16_as_ushort(f2b(d0x*rstd*g0.x + b0.x));
  o0.y = __bfloat16_as_ushort(f2b(d0y*rstd*g0.y + b0.y));
  o0.z = __bfloat16_as_ushort(f2b(d0z*rstd*g0.z + b0.z));
  o0.w = __bfloat16_as_ushort(f2b(d0w*rstd*g0.w + b0.w));
  o1.x = __bfloat16_as_ushort(f2b(d1x*rstd*g1.x + b1.x));
  o1.y = __bfloat16_as_ushort(f2b(d1y*rstd*g1.y + b1.y));
  o1.z = __bfloat16_as_ushort(f2b(d1z*rstd*g1.z + b1.z));
  o1.w = __bfloat16_as_ushort(f2b(d1w*rstd*g1.w + b1.w));
  ushort4* orow = (ushort4*)(out + (size_t)row*512);
  orow[lane] = o0;
  orow[lane + 64] = o1;
}

// ---------------- final LN+mean (blocks 0..2047) + MLP weight conv ---------
__global__ __launch_bounds__(256) void finalln_mlp_kernel(
    const float* __restrict__ h, const float* __restrict__ g,
    const float* __restrict__ b, bf16* __restrict__ feat,
    const float4* __restrict__ w1, const float4* __restrict__ w2,
    ushort4* __restrict__ o1, ushort4* __restrict__ o2)
{
  __shared__ float red[4];
  const int tid = threadIdx.x;
  if (blockIdx.x < 2048){
    const int n = blockIdx.x, t = tid;
    float a0 = 0.f, a1 = 0.f;
    for (int tt = 0; tt < 4; ++tt){
      const float* xr = h + ((size_t)n*4 + tt)*512;
      float v0 = xr[t], v1 = xr[t+256];
      float sv = v0 + v1;
      #pragma unroll
      for (int o = 32; o > 0; o >>= 1) sv += __shfl_down(sv, o, 64);
      int lane = tid & 63, wid = tid >> 6;
      if (lane == 0) red[wid] = sv;
      __syncthreads();
      float s = red[0] + red[1] + red[2] + red[3];
      __syncthreads();
      float mu = s * (1.f/512.f);
      float d0 = v0 - mu, d1 = v1 - mu;
      float q = d0*d0 + d1*d1;
      #pragma unroll
      for (int o = 32; o > 0; o >>= 1) q += __shfl_down(q, o, 64);
      if (lane == 0) red[wid] = q;
      __syncthreads();
      float sq = red[0] + red[1] + red[2] + red[3];
      __syncthreads();
      float rstd = rsqrtf(sq * (1.f/512.f) + 1e-5f);
      a0 += d0*rstd*g[t]     + b[t];
      a1 += d1*rstd*g[t+256] + b[t+256];
    }
    feat[(size_t)n*512 + t]       = f2b(a0 * 0.25f);
    feat[(size_t)n*512 + t + 256] = f2b(a1 * 0.25f);
  } else {
    for (int i = (blockIdx.x - 2048)*256 + tid; i < 4718592; i += 4096*256){
      if (i < 524288) o1[i] = cvt4(w1[i]);
      else            o2[i - 524288] = cvt4(w2[i - 524288]);
    }
  }
}

// ---------------- causal dwconv (both dirs) + silu, 4 ch/thread ------------
__global__ __launch_bounds__(256) void dwconv2_kernel(
    const bf16* __restrict__ xz, const float* __restrict__ cw,
    const float* __restrict__ cb, bf16* __restrict__ u)
{
  const int n = blockIdx.x;
  const int c4 = threadIdx.x * 4;
  ushort4 in4[4];
  #pragma unroll
  for (int t = 0; t < 4; ++t)
    in4[t] = *reinterpret_cast<const ushort4*>(&xz[((size_t)n*4 + t)*2048 + c4]);
  #pragma unroll
  for (int d = 0; d < 2; ++d){
    const float* cwd = cw + d*4096;
    const float* cbd = cb + d*1024;
    ushort4 out[4];
    #pragma unroll
    for (int j = 0; j < 4; ++j){
      float xa[4];
      #pragma unroll
      for (int t = 0; t < 4; ++t){
        int ts = d ? 3 - t : t;
        unsigned short us = j==0?in4[ts].x : j==1?in4[ts].y : j==2?in4[ts].z : in4[ts].w;
        xa[t] = u2f(us);
      }
      float4 wv = *reinterpret_cast<const float4*>(&cwd[(c4 + j)*4]);
      float bb = cbd[c4 + j];
      float o[4];
      o[0] = xa[0]*wv.w + bb;
      o[1] = xa[0]*wv.z + xa[1]*wv.w + bb;
      o[2] = xa[0]*wv.y + xa[1]*wv.z + xa[2]*wv.w + bb;
      o[3] = xa[0]*wv.x + xa[1]*wv.y + xa[2]*wv.z + xa[3]*wv.w + bb;
      #pragma unroll
      for (int t = 0; t < 4; ++t){
        float v = o[t];
        float sv = v / (1.f + __expf(-v));
        unsigned short us = __bfloat16_as_ushort(f2b(sv));
        if (j==0) out[t].x = us; else if (j==1) out[t].y = us;
        else if (j==2) out[t].z = us; else out[t].w = us;
      }
    }
    #pragma unroll
    for (int t = 0; t < 4; ++t)
      *reinterpret_cast<ushort4*>(&u[(size_t)d*8388608 + ((size_t)n*4 + t)*1024 + c4]) = out[t];
  }
}

// ---------------- fused bidirectional scan + gate --------------------------
__global__ __launch_bounds__(256) void scan2_kernel(
    const float* __restrict__ dbl, const bf16* __restrict__ dt2,
    const bf16* __restrict__ u, const bf16* __restrict__ xz,
    const float* __restrict__ Atab2, const float* __restrict__ Dp,
    bf16* __restrict__ gated)
{
  __shared__ float Bs[2][4][16], Cs[2][4][16];
  const int n = blockIdx.x, g = blockIdx.y, tid = threadIdx.x;
  {
    int t = tid >> 6, j = tid & 63;
    int d = j >> 5, jj = j & 31;
    float v = dbl[((size_t)n*4 + t)*128 + d*64 + jj];
    if (jj < 16) Bs[d][t][jj] = v; else Cs[d][t][jj-16] = v;
  }
  __syncthreads();
  const int c = g*256 + tid;
  const size_t base = (size_t)n*4*1024 + c;
  float yo0[4], yo1[4];
  float hs[16];
  // ---- direction 0 ----
  {
    float A[16];
    const float4* ap = reinterpret_cast<const float4*>(Atab2 + (size_t)c*16);
    #pragma unroll
    for (int q = 0; q < 4; ++q){
      float4 v = ap[q];
      A[q*4+0]=v.x; A[q*4+1]=v.y; A[q*4+2]=v.z; A[q*4+3]=v.w;
    }
    const float Dpc = Dp[c];
    #pragma unroll
    for (int s = 0; s < 16; ++s) hs[s] = 0.f;
    #pragma unroll
    for (int t = 0; t < 4; ++t){
      float dtv = bfu(dt2[base + (size_t)t*1024]);
      float uv  = bfu(u  [base + (size_t)t*1024]);
      float du = dtv * uv;
      float yv = 0.f;
      #pragma unroll
      for (int s = 0; s < 16; ++s){
        float dA = __builtin_amdgcn_exp2f(dtv * A[s]);
        hs[s] = dA * hs[s] + du * Bs[0][t][s];
        yv += hs[s] * Cs[0][t][s];
      }
      yo0[t] = yv + uv * Dpc;
    }
  }
  // ---- direction 1 (time-reversed input; output flipped) ----
  {
    float A[16];
    const float4* ap = reinterpret_cast<const float4*>(Atab2 + 16384 + (size_t)c*16);
    #pragma unroll
    for (int q = 0; q < 4; ++q){
      float4 v = ap[q];
      A[q*4+0]=v.x; A[q*4+1]=v.y; A[q*4+2]=v.z; A[q*4+3]=v.w;
    }
    const float Dpc = Dp[1024 + c];
    #pragma unroll
    for (int s = 0; s < 16; ++s) hs[s] = 0.f;
    #pragma unroll
    for (int t = 0; t < 4; ++t){
      float dtv = bfu(dt2[8388608 + base + (size_t)t*1024]);
      float uv  = bfu(u  [8388608 + base + (size_t)t*1024]);
      float du = dtv * uv;
      float yv = 0.f;
      #pragma unroll
      for (int s = 0; s < 16; ++s){
        float dA = __builtin_amdgcn_exp2f(dtv * A[s]);
        hs[s] = dA * hs[s] + du * Bs[1][t][s];
        yv += hs[s] * Cs[1][t][s];
      }
      yo1[3 - t] = yv + uv * Dpc;
    }
  }
  // ---- gate + store (same thread wrote/read only channel c) ----
  #pragma unroll
  for (int t = 0; t < 4; ++t){
    float z = bfu(xz[(size_t)(n*4 + t)*2048 + 1024 + c]);
    float sv = z / (1.f + __expf(-z));
    gated[base + (size_t)t*1024] = f2b((yo0[t] + yo1[t]) * sv);
  }
}

// ---------------- launch ---------------------------------------------------
extern "C" void kernel_launch(void* const* d_in, const int* in_sizes, int n_in,
                              void* d_out, int out_size, void* d_ws, size_t ws_size,
                              hipStream_t stream)
{
  const float* x_flat    = (const float*)d_in[0];
  const float* conv_a_w  = (const float*)d_in[1];
  const float* conv_p_w  = (const float*)d_in[2];
  const float* se_w1     = (const float*)d_in[3];
  const float* se_b1     = (const float*)d_in[4];
  const float* se_w2     = (const float*)d_in[5];
  const float* se_b2     = (const float*)d_in[6];
  const float* ln_g      = (const float*)d_in[7];
  const float* ln_b      = (const float*)d_in[8];
  const float* in_proj_w = (const float*)d_in[9];
  const float* conv_w    = (const float*)d_in[10];
  const float* conv_b    = (const float*)d_in[11];
  const float* x_proj_w  = (const float*)d_in[12];
  const float* dt_proj_w = (const float*)d_in[13];
  const float* dt_proj_b = (const float*)d_in[14];
  const float* A_log     = (const float*)d_in[15];
  const float* D_param   = (const float*)d_in[16];
  const float* out_proj_w= (const float*)d_in[17];
  const float* out_ln_g  = (const float*)d_in[18];
  const float* out_ln_b  = (const float*)d_in[19];
  const float* mlp_w1    = (const float*)d_in[20];
  const float* mlp_b1    = (const float*)d_in[21];
  const float* mlp_w2    = (const float*)d_in[22];
  const float* mlp_b2    = (const float*)d_in[23];

  char* ws = (char*)d_ws;
  const size_t OFF_H    = 0;                       // f32  8192*512  = 16.78MB
  const size_t OFF_HN   = OFF_H    + 16777216;     // bf16 8192*512  (feat overlay)
  const size_t OFF_XZ   = OFF_HN   + 8388608;      // bf16 8192*2048 (z1 overlay)
  const size_t OFF_U    = OFF_XZ   + 33554432;     // bf16 u[2] 8192*1024
  const size_t OFF_SCR  = OFF_U    + 33554432;     // Aa(stem)/dbl+dtrb(layers)/wb1(MLP)
  const size_t OFF_YB   = OFF_SCR  + 25165824;     // Pm+wa+wp(stem)/dt2(layers)/wb2(MLP)
  const size_t OFF_WB   = OFF_YB   + 33554432;     // bf16 in_proj+out_proj
  const size_t OFF_WXP  = OFF_WB   + 6291456;      // bf16 packed x_proj
  const size_t OFF_WDT  = OFF_WXP  + 1048576;      // bf16 padded dt_proj
  const size_t OFF_ATAB = OFF_WDT  + 524288;       // f32  4*1024*16

  float* h    = (float*)(ws + OFF_H);
  bf16*  hn   = (bf16*) (ws + OFF_HN);
  bf16*  xz   = (bf16*) (ws + OFF_XZ);
  bf16*  u    = (bf16*) (ws + OFF_U);
  float* dbl  = (float*)(ws + OFF_SCR);
  bf16*  dtrb = (bf16*) (ws + OFF_SCR + 4194304);
  bf16*  dt2  = (bf16*) (ws + OFF_YB);
  bf16*  feat = (bf16*) (ws + OFF_HN);   // overlay
  bf16*  z1   = (bf16*) (ws + OFF_XZ);   // overlay
  bf16*  wbi  = (bf16*) (ws + OFF_WB);
  bf16*  wbo  = (bf16*) (ws + OFF_WB + 4194304);
  bf16*  wxp  = (bf16*) (ws + OFF_WXP);
  bf16*  wdtp = (bf16*) (ws + OFF_WDT);
  float* Atab = (float*)(ws + OFF_ATAB);
  bf16*  wb1  = (bf16*) (ws + OFF_SCR);  // overlay (MLP phase)
  bf16*  wb2  = (bf16*) (ws + OFF_YB);   // overlay (MLP phase)
  bf16*  Aa   = (bf16*) (ws + OFF_SCR);
  bf16*  Pm   = (bf16*) (ws + OFF_YB);
  bf16*  wa   = (bf16*) (ws + OFF_YB + 8388608);
  bf16*  wp   = (bf16*) (ws + OFF_YB + 8388608 + 786432);
  float* outf = (float*)d_out;

  prep_im2col_kernel<<<4096, 256, 0, stream>>>(
      x_flat, conv_a_w, conv_p_w, in_proj_w, out_proj_w, x_proj_w, dt_proj_w,
      A_log, Aa, Pm, wa, wp, wbi, wbo, wxp, wdtp, Atab);

  stemgemm_kernel<<<dim3(64,4), 256, 0, stream>>>(Aa, wa, Pm, wp, h);

  se_ln_kernel<<<2048, 256, 0, stream>>>(
      se_w1, se_b1, se_w2, se_b2, ln_g, ln_b, h, hn);

  for (int l = 0; l < 2; ++l){
    if (l == 1)
      ln_kernel<<<2048, 256, 0, stream>>>(h, ln_g + 512, ln_b + 512, hn);
    mgemm_kernel<0,0,false><<<dim3(64,16), 256, 0, stream>>>(
        hn, wbi + (size_t)l*2048*512, nullptr, xz, 512, 2048);
    dwconv2_kernel<<<2048, 256, 0, stream>>>(
        xz, conv_w + (size_t)l*8192, conv_b + (size_t)l*2048, u);
    bgemm_kernel<<<dim3(64,2), 256, 0, stream>>>(
        u, wxp + (size_t)l*262144, dtrb, dbl);
    dtgemm_kernel<<<dim3(128,8), 256, 0, stream>>>(
        dtrb, wdtp + (size_t)l*131072, dt_proj_b + (size_t)l*2048, dt2);
    scan2_kernel<<<dim3(2048,4), 256, 0, stream>>>(
        dbl, dt2, u, xz, Atab + (size_t)l*32768, D_param + (size_t)l*2048,
        u /* gated overlays u dir0 */);
    mgemm128_kernel<0,2,false><<<dim3(64,4), 256, 0, stream>>>(
        u, wbo + (size_t)l*512*1024, nullptr, h, 1024, 512);
  }

  finalln_mlp_kernel<<<6144, 256, 0, stream>>>(
      h, out_ln_g, out_ln_b, feat,
      (const float4*)mlp_w1, (const float4*)mlp_w2, (ushort4*)wb1, (ushort4*)wb2);

  mgemm128_kernel<1,0,true><<<dim3(16,32), 256, 0, stream>>>(
      feat, wb1, mlp_b1, z1, 512, 4096);
  mgemm128_kernel<1,1,true><<<dim3(16,32), 256, 0, stream>>>(
      z1, wb2, mlp_b2, outf, 4096, 4096);
}

// Round 16
// 635.728 us; speedup vs baseline: 1.0330x; 1.0041x over previous
//
#include <hip/hip_runtime.h>
#include <hip/hip_bf16.h>

typedef __hip_bfloat16 bf16;
typedef __attribute__((ext_vector_type(8))) short s16x8;
typedef __attribute__((ext_vector_type(4))) float f32x4;

__device__ __forceinline__ float u2f(unsigned short u){
  union { unsigned int i; float f; } v; v.i = ((unsigned int)u) << 16; return v.f;
}
__device__ __forceinline__ float bfu(bf16 x){ return __bfloat162float(x); }
__device__ __forceinline__ bf16  f2b(float x){ return __float2bfloat16(x); }

__device__ __forceinline__ void gload16(const void* g, void* l){
  __builtin_amdgcn_global_load_lds(
      (const __attribute__((address_space(1))) void*)g,
      (__attribute__((address_space(3))) void*)l, 16, 0, 0);
}

__device__ __forceinline__ float wave_sum(float v){
  #pragma unroll
  for (int o = 1; o < 64; o <<= 1) v += __shfl_xor(v, o, 64);
  return v;
}

__device__ __forceinline__ ushort4 cvt4(float4 v){
  ushort4 o;
  o.x = __bfloat16_as_ushort(f2b(v.x));
  o.y = __bfloat16_as_ushort(f2b(v.y));
  o.z = __bfloat16_as_ushort(f2b(v.z));
  o.w = __bfloat16_as_ushort(f2b(v.w));
  return o;
}

// ---------------- prep + im2col in ONE dispatch (grid 4096) ----------------
__global__ __launch_bounds__(256) void prep_im2col_kernel(
    const float* __restrict__ x_flat,
    const float* __restrict__ caw, const float* __restrict__ cpw,
    const float* __restrict__ ipw, const float* __restrict__ opw,
    const float* __restrict__ xpw, const float* __restrict__ dtw,
    const float* __restrict__ alog,
    bf16* __restrict__ Aa, bf16* __restrict__ P,
    bf16* __restrict__ wa, bf16* __restrict__ wp,
    bf16* __restrict__ wbi, bf16* __restrict__ wbo,
    bf16* __restrict__ wxp, bf16* __restrict__ wdtp,
    float* __restrict__ atab)
{
  __shared__ float xs[512][8];
  const int tid = threadIdx.x;
  if (blockIdx.x < 2048){
    const int n = blockIdx.x;
    const float* xr = x_flat + (size_t)n * 3584;
    for (int i = tid; i < 3584; i += 256) xs[i / 7][i % 7] = xr[i];
    __syncthreads();
    bf16* Ar = Aa + (size_t)n * 4 * 1536;
    for (int i = tid; i < 6144; i += 256){
      int t = i / 1536, col = i - t*1536;
      int c = col / 3, kk = col - c*3;
      int p = 2*t - 1 + kk;
      float v = (p >= 0 && p < 7) ? xs[c][p] : 0.f;
      Ar[i] = f2b(v);
    }
    bf16* Pr = P + (size_t)n * 4 * 512;
    for (int i = tid; i < 2048; i += 256){
      int t = i >> 9, c = i & 511;
      int st = 2*t - 1;
      float m = -1e30f;
      #pragma unroll
      for (int k = 0; k < 3; ++k){ int p = st + k; if (p >= 0 && p < 7) m = fmaxf(m, xs[c][p]); }
      Pr[i] = f2b(m);
    }
  } else {
    for (int i = (blockIdx.x - 2048)*256 + tid; i < 1769472; i += 2048*256){
      if (i < 917504){
        int j = i;
        const float4* src; ushort4* dst;
        if (j < 98304)      { src = (const float4*)caw; dst = (ushort4*)wa; }
        else if (j < 131072){ j -= 98304;  src = (const float4*)cpw; dst = (ushort4*)wp; }
        else if (j < 655360){ j -= 131072; src = (const float4*)ipw; dst = (ushort4*)wbi; }
        else                { j -= 655360; src = (const float4*)opw; dst = (ushort4*)wbo; }
        dst[j] = cvt4(src[j]);
      } else if (i < 1441792){
        int idx = i - 917504;                 // xpw pad: [L][2*128][1024]
        int l = idx >> 18, rem = idx & 262143, row = rem >> 10, c = rem & 1023;
        int d = row >> 7, r = row & 127;
        float v = (r < 64) ? xpw[(((size_t)l*2 + d)*64 + r)*1024 + c] : 0.f;
        wxp[idx] = f2b(v);
      } else if (i < 1703936){
        int idx = i - 1441792;                // wdt pad: [4][1024][64]
        int ld = idx >> 16, rem = idx & 65535, r = rem >> 6, cc = rem & 63;
        float v = (cc < 32) ? dtw[((size_t)ld*1024 + r)*32 + cc] : 0.f;
        wdtp[idx] = f2b(v);
      } else {
        int idx = i - 1703936;                // atab (pre-scaled by log2 e)
        atab[idx] = -__expf(alog[idx]) * 1.44269504088896f;
      }
    }
  }
}

// ---------------- MFMA GEMM (BK=64): out = act(A·Wᵀ + bias) ---------------
template<int ACT, int OMODE, bool HASBIAS>
__global__ __launch_bounds__(256) void mgemm_kernel(
    const bf16* __restrict__ A, const bf16* __restrict__ W,
    const float* __restrict__ bias, void* __restrict__ outp,
    int K, int ldo)
{
  __shared__ char lsA[16384];
  __shared__ char lsB[16384];
  const int tid = threadIdx.x;
  const int w = tid >> 6, l = tid & 63;
  const int nwg = gridDim.x * gridDim.y;
  const int lin = blockIdx.y * gridDim.x + blockIdx.x;
  const int cpx = nwg >> 3;
  const int swz = (lin & 7) * cpx + (lin >> 3);
  const int m0 = (swz % gridDim.x) * 128, n0 = (swz / gridDim.x) * 128;
  const int wr = w >> 1, wc = w & 1;
  const size_t ldb = (size_t)K * 2;
  const char* Ab = (const char*)A + (size_t)m0 * ldb;
  const char* Wb = (const char*)W + (size_t)n0 * ldb;

  const int srow = l >> 3;
  const int scb  = ((l & 7) ^ srow) << 4;
  const int fr = l & 15;
  const int fg = l >> 4;
  const int fsw = (fr & 7) << 4;

  f32x4 acc[4][4];
  #pragma unroll
  for (int m = 0; m < 4; ++m)
    #pragma unroll
    for (int n = 0; n < 4; ++n) acc[m][n] = (f32x4){0.f,0.f,0.f,0.f};

  const int nk = K >> 6;
  for (int kt = 0; kt < nk; ++kt){
    const char* As = Ab + (size_t)kt * 128;
    const char* Ws = Wb + (size_t)kt * 128;
    #pragma unroll
    for (int i = 0; i < 4; ++i){
      int row = (i*4 + w)*8 + srow;
      gload16(As + (size_t)row*ldb + scb, &lsA[(i*4 + w)*1024]);
    }
    #pragma unroll
    for (int i = 0; i < 4; ++i){
      int row = (i*4 + w)*8 + srow;
      gload16(Ws + (size_t)row*ldb + scb, &lsB[(i*4 + w)*1024]);
    }
    __syncthreads();

    s16x8 af[4][2], bfr[4][2];
    #pragma unroll
    for (int m = 0; m < 4; ++m){
      int row = wr*64 + m*16 + fr;
      af[m][0] = *(const s16x8*)&lsA[row*128 + (( 0 + fg*16) ^ fsw)];
      af[m][1] = *(const s16x8*)&lsA[row*128 + ((64 + fg*16) ^ fsw)];
    }
    #pragma unroll
    for (int n = 0; n < 4; ++n){
      int row = wc*64 + n*16 + fr;
      bfr[n][0] = *(const s16x8*)&lsB[row*128 + (( 0 + fg*16) ^ fsw)];
      bfr[n][1] = *(const s16x8*)&lsB[row*128 + ((64 + fg*16) ^ fsw)];
    }
    #pragma unroll
    for (int m = 0; m < 4; ++m)
      #pragma unroll
      for (int n = 0; n < 4; ++n){
        acc[m][n] = __builtin_amdgcn_mfma_f32_16x16x32_bf16(af[m][0], bfr[n][0], acc[m][n], 0, 0, 0);
        acc[m][n] = __builtin_amdgcn_mfma_f32_16x16x32_bf16(af[m][1], bfr[n][1], acc[m][n], 0, 0, 0);
      }
    __syncthreads();
  }

  const int orow0 = m0 + wr*64, ocol0 = n0 + wc*64;
  #pragma unroll
  for (int n = 0; n < 4; ++n){
    int col = ocol0 + n*16 + fr;
    float bv = HASBIAS ? bias[col] : 0.f;
    #pragma unroll
    for (int m = 0; m < 4; ++m){
      int rbase = orow0 + m*16 + fg*4;
      #pragma unroll
      for (int r = 0; r < 4; ++r){
        float v = acc[m][n][r] + bv;
        if (ACT == 1) v = fmaxf(v, 0.f);
        if (ACT == 2) v = (v > 20.f) ? v : log1pf(__expf(v));
        size_t oi = (size_t)(rbase + r) * ldo + col;
        if (OMODE == 0)      ((bf16*)outp)[oi] = f2b(v);
        else if (OMODE == 1) ((float*)outp)[oi] = v;
        else                 ((float*)outp)[oi] += v;
      }
    }
  }
}

// ---------------- batched stem GEMM: conv_a + conv_p in ONE dispatch -------
__global__ __launch_bounds__(256) void stemgemm_kernel(
    const bf16* __restrict__ Aa, const bf16* __restrict__ wa,
    const bf16* __restrict__ Pm, const bf16* __restrict__ wp,
    float* __restrict__ h)
{
  __shared__ char lsA[16384];
  __shared__ char lsB[16384];
  const int tid = threadIdx.x;
  const int w = tid >> 6, l = tid & 63;
  const int lin = blockIdx.y * gridDim.x + blockIdx.x;  // 256 blocks
  const int swz = (lin & 7) * 32 + (lin >> 3);
  const int tm = swz & 63, ty = swz >> 6;
  const int m0 = tm * 128;
  const bf16* A;
  const bf16* W;
  int K;
  if (ty < 2){ A = Aa; W = wa + (size_t)(ty)*128*1536; K = 1536; }
  else       { A = Pm; W = wp + (size_t)(ty-2)*128*512; K = 512; }
  const int wr = w >> 1, wc = w & 1;
  const size_t ldb = (size_t)K * 2;
  const char* Ab = (const char*)A + (size_t)m0 * ldb;
  const char* Wb = (const char*)W;

  const int srow = l >> 3;
  const int scb  = ((l & 7) ^ srow) << 4;
  const int fr = l & 15;
  const int fg = l >> 4;
  const int fsw = (fr & 7) << 4;

  f32x4 acc[4][4];
  #pragma unroll
  for (int m = 0; m < 4; ++m)
    #pragma unroll
    for (int n = 0; n < 4; ++n) acc[m][n] = (f32x4){0.f,0.f,0.f,0.f};

  const int nk = K >> 6;
  for (int kt = 0; kt < nk; ++kt){
    const char* As = Ab + (size_t)kt * 128;
    const char* Ws = Wb + (size_t)kt * 128;
    #pragma unroll
    for (int i = 0; i < 4; ++i){
      int row = (i*4 + w)*8 + srow;
      gload16(As + (size_t)row*ldb + scb, &lsA[(i*4 + w)*1024]);
    }
    #pragma unroll
    for (int i = 0; i < 4; ++i){
      int row = (i*4 + w)*8 + srow;
      gload16(Ws + (size_t)row*ldb + scb, &lsB[(i*4 + w)*1024]);
    }
    __syncthreads();

    s16x8 af[4][2], bfr[4][2];
    #pragma unroll
    for (int m = 0; m < 4; ++m){
      int row = wr*64 + m*16 + fr;
      af[m][0] = *(const s16x8*)&lsA[row*128 + (( 0 + fg*16) ^ fsw)];
      af[m][1] = *(const s16x8*)&lsA[row*128 + ((64 + fg*16) ^ fsw)];
    }
    #pragma unroll
    for (int n = 0; n < 4; ++n){
      int row = wc*64 + n*16 + fr;
      bfr[n][0] = *(const s16x8*)&lsB[row*128 + (( 0 + fg*16) ^ fsw)];
      bfr[n][1] = *(const s16x8*)&lsB[row*128 + ((64 + fg*16) ^ fsw)];
    }
    #pragma unroll
    for (int m = 0; m < 4; ++m)
      #pragma unroll
      for (int n = 0; n < 4; ++n){
        acc[m][n] = __builtin_amdgcn_mfma_f32_16x16x32_bf16(af[m][0], bfr[n][0], acc[m][n], 0, 0, 0);
        acc[m][n] = __builtin_amdgcn_mfma_f32_16x16x32_bf16(af[m][1], bfr[n][1], acc[m][n], 0, 0, 0);
      }
    __syncthreads();
  }

  const int orow0 = m0 + wr*64, ocol0 = ty*128 + wc*64;
  #pragma unroll
  for (int n = 0; n < 4; ++n){
    int col = ocol0 + n*16 + fr;
    #pragma unroll
    for (int m = 0; m < 4; ++m){
      int rbase = orow0 + m*16 + fg*4;
      #pragma unroll
      for (int r = 0; r < 4; ++r)
        h[(size_t)(rbase + r)*512 + col] = fmaxf(acc[m][n][r], 0.f);
    }
  }
}

// ---------------- MFMA GEMM (BK=128): half the barriers, 4-bit XOR swizzle -
template<int ACT, int OMODE, bool HASBIAS>
__global__ __launch_bounds__(256) void mgemm128_kernel(
    const bf16* __restrict__ A, const bf16* __restrict__ W,
    const float* __restrict__ bias, void* __restrict__ outp,
    int K, int ldo)
{
  __shared__ char lsA[32768];
  __shared__ char lsB[32768];
  const int tid = threadIdx.x;
  const int w = tid >> 6, l = tid & 63;
  const int nwg = gridDim.x * gridDim.y;
  const int lin = blockIdx.y * gridDim.x + blockIdx.x;
  const int cpx = nwg >> 3;
  const int swz = (lin & 7) * cpx + (lin >> 3);
  const int m0 = (swz % gridDim.x) * 128, n0 = (swz / gridDim.x) * 128;
  const int wr = w >> 1, wc = w & 1;
  const size_t ldb = (size_t)K * 2;
  const char* Ab = (const char*)A + (size_t)m0 * ldb;
  const char* Wb = (const char*)W + (size_t)n0 * ldb;

  const int srow4 = l >> 4;
  const int slot  = l & 15;
  const int fr = l & 15;
  const int fg = l >> 4;
  const int fx = fr;                   // FULL 4-bit row XOR (row&15 == fr)

  f32x4 acc[4][4];
  #pragma unroll
  for (int m = 0; m < 4; ++m)
    #pragma unroll
    for (int n = 0; n < 4; ++n) acc[m][n] = (f32x4){0.f,0.f,0.f,0.f};

  const int nk = K >> 7;
  for (int kt = 0; kt < nk; ++kt){
    const char* As = Ab + (size_t)kt * 256;
    const char* Ws = Wb + (size_t)kt * 256;
    #pragma unroll
    for (int i = 0; i < 8; ++i){
      int c = i*4 + w;
      int row = c*4 + srow4;
      int colb = (slot ^ (row & 15)) << 4;   // 4-bit source swizzle
      gload16(As + (size_t)row*ldb + colb, &lsA[c*1024]);
      gload16(Ws + (size_t)row*ldb + colb, &lsB[c*1024]);
    }
    __syncthreads();

    #pragma unroll
    for (int half = 0; half < 2; ++half){
      s16x8 af[4][2], bfr[4][2];
      #pragma unroll
      for (int m = 0; m < 4; ++m){
        int row = wr*64 + m*16 + fr;
        af[m][0] = *(const s16x8*)&lsA[row*256 + ((((half*2+0)*4 + fg) ^ fx) << 4)];
        af[m][1] = *(const s16x8*)&lsA[row*256 + ((((half*2+1)*4 + fg) ^ fx) << 4)];
      }
      #pragma unroll
      for (int n = 0; n < 4; ++n){
        int row = wc*64 + n*16 + fr;
        bfr[n][0] = *(const s16x8*)&lsB[row*256 + ((((half*2+0)*4 + fg) ^ fx) << 4)];
        bfr[n][1] = *(const s16x8*)&lsB[row*256 + ((((half*2+1)*4 + fg) ^ fx) << 4)];
      }
      #pragma unroll
      for (int m = 0; m < 4; ++m)
        #pragma unroll
        for (int n = 0; n < 4; ++n){
          acc[m][n] = __builtin_amdgcn_mfma_f32_16x16x32_bf16(af[m][0], bfr[n][0], acc[m][n], 0, 0, 0);
          acc[m][n] = __builtin_amdgcn_mfma_f32_16x16x32_bf16(af[m][1], bfr[n][1], acc[m][n], 0, 0, 0);
        }
    }
    __syncthreads();
  }

  const int orow0 = m0 + wr*64, ocol0 = n0 + wc*64;
  #pragma unroll
  for (int n = 0; n < 4; ++n){
    int col = ocol0 + n*16 + fr;
    float bv = HASBIAS ? bias[col] : 0.f;
    #pragma unroll
    for (int m = 0; m < 4; ++m){
      int rbase = orow0 + m*16 + fg*4;
      #pragma unroll
      for (int r = 0; r < 4; ++r){
        float v = acc[m][n][r] + bv;
        if (ACT == 1) v = fmaxf(v, 0.f);
        if (ACT == 2) v = (v > 20.f) ? v : log1pf(__expf(v));
        size_t oi = (size_t)(rbase + r) * ldo + col;
        if (OMODE == 0)      ((bf16*)outp)[oi] = f2b(v);
        else if (OMODE == 1) ((float*)outp)[oi] = v;
        else                 ((float*)outp)[oi] += v;
      }
    }
  }
}

// ---------------- batched x_proj GEMM ---------------------------------------
__global__ __launch_bounds__(256) void bgemm_kernel(
    const bf16* __restrict__ A, const bf16* __restrict__ W,
    bf16* __restrict__ dtr_buf, float* __restrict__ dbl)
{
  __shared__ char lsA[16384];
  __shared__ char lsB[16384];
  const int tid = threadIdx.x;
  const int w = tid >> 6, l = tid & 63;
  const int nwg = gridDim.x * 2;
  const int lin = blockIdx.y * gridDim.x + blockIdx.x;
  const int cpx = nwg >> 3;
  const int swz = (lin & 7) * cpx + (lin >> 3);
  const int m0 = (swz % gridDim.x) * 128;
  const int d  = swz / gridDim.x;
  const int K = 1024;
  const int wr = w >> 1, wc = w & 1;
  const size_t ldb = (size_t)K * 2;
  const char* Ab = (const char*)(A + (size_t)d*8388608) + (size_t)m0 * ldb;
  const char* Wb = (const char*)(W + (size_t)d*131072);

  const int srow = l >> 3;
  const int scb  = ((l & 7) ^ srow) << 4;
  const int fr = l & 15;
  const int fg = l >> 4;
  const int fsw = (fr & 7) << 4;

  f32x4 acc[4][4];
  #pragma unroll
  for (int m = 0; m < 4; ++m)
    #pragma unroll
    for (int n = 0; n < 4; ++n) acc[m][n] = (f32x4){0.f,0.f,0.f,0.f};

  const int nk = K >> 6;
  for (int kt = 0; kt < nk; ++kt){
    const char* As = Ab + (size_t)kt * 128;
    const char* Ws = Wb + (size_t)kt * 128;
    #pragma unroll
    for (int i = 0; i < 4; ++i){
      int row = (i*4 + w)*8 + srow;
      gload16(As + (size_t)row*ldb + scb, &lsA[(i*4 + w)*1024]);
    }
    #pragma unroll
    for (int i = 0; i < 4; ++i){
      int row = (i*4 + w)*8 + srow;
      gload16(Ws + (size_t)row*ldb + scb, &lsB[(i*4 + w)*1024]);
    }
    __syncthreads();

    s16x8 af[4][2], bfr[4][2];
    #pragma unroll
    for (int m = 0; m < 4; ++m){
      int row = wr*64 + m*16 + fr;
      af[m][0] = *(const s16x8*)&lsA[row*128 + (( 0 + fg*16) ^ fsw)];
      af[m][1] = *(const s16x8*)&lsA[row*128 + ((64 + fg*16) ^ fsw)];
    }
    #pragma unroll
    for (int n = 0; n < 4; ++n){
      int row = wc*64 + n*16 + fr;
      bfr[n][0] = *(const s16x8*)&lsB[row*128 + (( 0 + fg*16) ^ fsw)];
      bfr[n][1] = *(const s16x8*)&lsB[row*128 + ((64 + fg*16) ^ fsw)];
    }
    #pragma unroll
    for (int m = 0; m < 4; ++m)
      #pragma unroll
      for (int n = 0; n < 4; ++n){
        acc[m][n] = __builtin_amdgcn_mfma_f32_16x16x32_bf16(af[m][0], bfr[n][0], acc[m][n], 0, 0, 0);
        acc[m][n] = __builtin_amdgcn_mfma_f32_16x16x32_bf16(af[m][1], bfr[n][1], acc[m][n], 0, 0, 0);
      }
    __syncthreads();
  }

  const int orow0 = m0 + wr*64, c0 = wc*64;
  #pragma unroll
  for (int n = 0; n < 4; ++n){
    int col = c0 + n*16 + fr;
    #pragma unroll
    for (int m = 0; m < 4; ++m){
      int rbase = orow0 + m*16 + fg*4;
      #pragma unroll
      for (int r = 0; r < 4; ++r){
        float v = acc[m][n][r];
        int row = rbase + r;
        if (col < 32)
          dtr_buf[((size_t)d*8192 + row)*64 + col] = f2b(v);
        else if (col < 64)
          dbl[(size_t)row*128 + d*64 + (col - 32)] = v;
        else if (col < 96)
          dtr_buf[((size_t)d*8192 + row)*64 + (col - 32)] = f2b(v);  // pad zeros
      }
    }
  }
}

// ---------------- dt_proj GEMM, both dirs in one dispatch ------------------
__global__ __launch_bounds__(256) void dtgemm_kernel(
    const bf16* __restrict__ A, const bf16* __restrict__ W2,
    const float* __restrict__ bias2, bf16* __restrict__ out2)
{
  __shared__ char lsA[16384];
  __shared__ char lsB[16384];
  const int tid = threadIdx.x;
  const int w = tid >> 6, l = tid & 63;
  const int nwg = gridDim.x * gridDim.y;          // 1024
  const int lin = blockIdx.y * gridDim.x + blockIdx.x;
  const int cpx = nwg >> 3;
  const int swz = (lin & 7) * cpx + (lin >> 3);
  const int m0 = (swz % gridDim.x) * 128, n0 = (swz / gridDim.x) * 128;
  const int d  = (m0 >= 8192) ? 1 : 0;
  const int wr = w >> 1, wc = w & 1;
  const size_t ldb = 128;
  const char* Ab = (const char*)A + (size_t)m0 * ldb;
  const char* Wb = (const char*)(W2 + (size_t)d*65536) + (size_t)n0 * ldb;
  const float* bias = bias2 + d*1024;
  bf16* outp = out2 + (size_t)d*8388608;

  const int srow = l >> 3;
  const int scb  = ((l & 7) ^ srow) << 4;
  const int fr = l & 15, fg = l >> 4;
  const int fsw = (fr & 7) << 4;

  f32x4 acc[4][4];
  #pragma unroll
  for (int m = 0; m < 4; ++m)
    #pragma unroll
    for (int n = 0; n < 4; ++n) acc[m][n] = (f32x4){0.f,0.f,0.f,0.f};

  #pragma unroll
  for (int i = 0; i < 4; ++i){
    int row = (i*4 + w)*8 + srow;
    gload16(Ab + (size_t)row*ldb + scb, &lsA[(i*4 + w)*1024]);
  }
  #pragma unroll
  for (int i = 0; i < 4; ++i){
    int row = (i*4 + w)*8 + srow;
    gload16(Wb + (size_t)row*ldb + scb, &lsB[(i*4 + w)*1024]);
  }
  __syncthreads();

  s16x8 af[4][2], bfr[4][2];
  #pragma unroll
  for (int m = 0; m < 4; ++m){
    int row = wr*64 + m*16 + fr;
    af[m][0] = *(const s16x8*)&lsA[row*128 + (( 0 + fg*16) ^ fsw)];
    af[m][1] = *(const s16x8*)&lsA[row*128 + ((64 + fg*16) ^ fsw)];
  }
  #pragma unroll
  for (int n = 0; n < 4; ++n){
    int row = wc*64 + n*16 + fr;
    bfr[n][0] = *(const s16x8*)&lsB[row*128 + (( 0 + fg*16) ^ fsw)];
    bfr[n][1] = *(const s16x8*)&lsB[row*128 + ((64 + fg*16) ^ fsw)];
  }
  #pragma unroll
  for (int m = 0; m < 4; ++m)
    #pragma unroll
    for (int n = 0; n < 4; ++n){
      acc[m][n] = __builtin_amdgcn_mfma_f32_16x16x32_bf16(af[m][0], bfr[n][0], acc[m][n], 0, 0, 0);
      acc[m][n] = __builtin_amdgcn_mfma_f32_16x16x32_bf16(af[m][1], bfr[n][1], acc[m][n], 0, 0, 0);
    }

  const int orow0 = (m0 - d*8192) + wr*64, ocol0 = n0 + wc*64;
  #pragma unroll
  for (int n = 0; n < 4; ++n){
    int col = ocol0 + n*16 + fr;
    float bv = bias[col];
    #pragma unroll
    for (int m = 0; m < 4; ++m){
      int rbase = orow0 + m*16 + fg*4;
      #pragma unroll
      for (int r = 0; r < 4; ++r){
        float v = acc[m][n][r] + bv;
        v = (v > 20.f) ? v : log1pf(__expf(v));          // softplus
        outp[(size_t)(rbase + r) * 1024 + col] = f2b(v);
      }
    }
  }
}

// ---------------- SE + layer-0 LN fused (one block per sample) -------------
__global__ __launch_bounds__(256) void se_ln_kernel(
    const float* __restrict__ sw1, const float* __restrict__ sb1,
    const float* __restrict__ sw2, const float* __restrict__ sb2,
    const float* __restrict__ g, const float* __restrict__ b,
    float* __restrict__ h, bf16* __restrict__ hn)
{
  __shared__ float yms[512];
  __shared__ float s1s[32];
  __shared__ float sg[512];
  const int n = blockIdx.x, tid = threadIdx.x;
  float* hb = h + (size_t)n * 2048;
  for (int c = tid; c < 512; c += 256)
    yms[c] = 0.25f * (hb[c] + hb[512+c] + hb[1024+c] + hb[1536+c]);
  __syncthreads();
  {
    int o = tid >> 3, sl = tid & 7;
    const float* wr = sw1 + (size_t)o * 512 + sl*64;
    const float* ym = yms + sl*64;
    float a = 0.f;
    #pragma unroll 16
    for (int i = 0; i < 64; ++i) a += wr[i] * ym[i];
    a += __shfl_down(a, 4, 8);
    a += __shfl_down(a, 2, 8);
    a += __shfl_down(a, 1, 8);
    if (sl == 0) s1s[o] = fmaxf(a + sb1[o], 0.f);
  }
  __syncthreads();
  for (int c = tid; c < 512; c += 256){
    float a = sb2[c];
    const float* wr = sw2 + (size_t)c * 32;
    #pragma unroll
    for (int j = 0; j < 32; ++j) a += wr[j] * s1s[j];
    sg[c] = 1.f / (1.f + __expf(-a));
  }
  __syncthreads();
  const int lane = tid & 63, wv = tid >> 6;
  float* hr = hb + wv*512;
  float4 v0 = ((float4*)hr)[lane], v1 = ((float4*)hr)[lane + 64];
  int c0 = lane*4, c1 = 256 + lane*4;
  v0.x *= sg[c0+0]; v0.y *= sg[c0+1]; v0.z *= sg[c0+2]; v0.w *= sg[c0+3];
  v1.x *= sg[c1+0]; v1.y *= sg[c1+1]; v1.z *= sg[c1+2]; v1.w *= sg[c1+3];
  ((float4*)hr)[lane] = v0;
  ((float4*)hr)[lane + 64] = v1;
  float s = wave_sum(v0.x+v0.y+v0.z+v0.w + v1.x+v1.y+v1.z+v1.w);
  float mu = s * (1.f/512.f);
  float d0x=v0.x-mu, d0y=v0.y-mu, d0z=v0.z-mu, d0w=v0.w-mu;
  float d1x=v1.x-mu, d1y=v1.y-mu, d1z=v1.z-mu, d1w=v1.w-mu;
  float sq = wave_sum(d0x*d0x+d0y*d0y+d0z*d0z+d0w*d0w +
                      d1x*d1x+d1y*d1y+d1z*d1z+d1w*d1w);
  float rstd = rsqrtf(sq * (1.f/512.f) + 1e-5f);
  float4 g0 = ((const float4*)g)[lane], g1 = ((const float4*)g)[lane+64];
  float4 b0 = ((const float4*)b)[lane], b1 = ((const float4*)b)[lane+64];
  ushort4 o0, o1;
  o0.x = __bfloat16_as_ushort(f2b(d0x*rstd*g0.x + b0.x));
  o0.y = __bfloat16_as_ushort(f2b(d0y*rstd*g0.y + b0.y));
  o0.z = __bfloat16_as_ushort(f2b(d0z*rstd*g0.z + b0.z));
  o0.w = __bfloat16_as_ushort(f2b(d0w*rstd*g0.w + b0.w));
  o1.x = __bfloat16_as_ushort(f2b(d1x*rstd*g1.x + b1.x));
  o1.y = __bfloat16_as_ushort(f2b(d1y*rstd*g1.y + b1.y));
  o1.z = __bfloat16_as_ushort(f2b(d1z*rstd*g1.z + b1.z));
  o1.w = __bfloat16_as_ushort(f2b(d1w*rstd*g1.w + b1.w));
  ushort4* orow = (ushort4*)(hn + ((size_t)n*4 + wv)*512);
  orow[lane] = o0;
  orow[lane + 64] = o1;
}

// ---------------- layernorm: wave-per-row, 4 rows/block, grid 2048 ---------
__global__ __launch_bounds__(256) void ln_kernel(
    const float* __restrict__ x, const float* __restrict__ g,
    const float* __restrict__ b, bf16* __restrict__ out)
{
  const int lane = threadIdx.x & 63, wid = threadIdx.x >> 6;
  const int row = blockIdx.x*4 + wid;
  const float4* xr = (const float4*)(x + (size_t)row*512);
  float4 v0 = xr[lane], v1 = xr[lane + 64];
  float s = wave_sum(v0.x+v0.y+v0.z+v0.w + v1.x+v1.y+v1.z+v1.w);
  float mu = s * (1.f/512.f);
  float d0x=v0.x-mu, d0y=v0.y-mu, d0z=v0.z-mu, d0w=v0.w-mu;
  float d1x=v1.x-mu, d1y=v1.y-mu, d1z=v1.z-mu, d1w=v1.w-mu;
  float sq = wave_sum(d0x*d0x+d0y*d0y+d0z*d0z+d0w*d0w +
                      d1x*d1x+d1y*d1y+d1z*d1z+d1w*d1w);
  float rstd = rsqrtf(sq * (1.f/512.f) + 1e-5f);
  float4 g0 = ((const float4*)g)[lane], g1 = ((const float4*)g)[lane+64];
  float4 b0 = ((const float4*)b)[lane], b1 = ((const float4*)b)[lane+64];
  ushort4 o0, o1;
  o0.x = __bfloat16_as_ushort(f2b(d0x*rstd*g0.x + b0.x));
  o0.y = __bfloat16_as_ushort(f2b(d0y*rstd*g0.y + b0.y));
  o0.z = __bfloat16_as_ushort(f2b(d0z*rstd*g0.z + b0.z));
  o0.w = __bfloat16_as_ushort(f2b(d0w*rstd*g0.w + b0.w));
  o1.x = __bfloat16_as_ushort(f2b(d1x*rstd*g1.x + b1.x));
  o1.y = __bfloat16_as_ushort(f2b(d1y*rstd*g1.y + b1.y));
  o1.z = __bfloat16_as_ushort(f2b(d1z*rstd*g1.z + b1.z));
  o1.w = __bfloat16_as_ushort(f2b(d1w*rstd*g1.w + b1.w));
  ushort4* orow = (ushort4*)(out + (size_t)row*512);
  orow[lane] = o0;
  orow[lane + 64] = o1;
}

// ---------------- final LN+mean (blocks 0..2047) + MLP weight conv ---------
__global__ __launch_bounds__(256) void finalln_mlp_kernel(
    const float* __restrict__ h, const float* __restrict__ g,
    const float* __restrict__ b, bf16* __restrict__ feat,
    const float4* __restrict__ w1, const float4* __restrict__ w2,
    ushort4* __restrict__ o1, ushort4* __restrict__ o2)
{
  __shared__ float red[4];
  const int tid = threadIdx.x;
  if (blockIdx.x < 2048){
    const int n = blockIdx.x, t = tid;
    float a0 = 0.f, a1 = 0.f;
    for (int tt = 0; tt < 4; ++tt){
      const float* xr = h + ((size_t)n*4 + tt)*512;
      float v0 = xr[t], v1 = xr[t+256];
      float sv = v0 + v1;
      #pragma unroll
      for (int o = 32; o > 0; o >>= 1) sv += __shfl_down(sv, o, 64);
      int lane = tid & 63, wid = tid >> 6;
      if (lane == 0) red[wid] = sv;
      __syncthreads();
      float s = red[0] + red[1] + red[2] + red[3];
      __syncthreads();
      float mu = s * (1.f/512.f);
      float d0 = v0 - mu, d1 = v1 - mu;
      float q = d0*d0 + d1*d1;
      #pragma unroll
      for (int o = 32; o > 0; o >>= 1) q += __shfl_down(q, o, 64);
      if (lane == 0) red[wid] = q;
      __syncthreads();
      float sq = red[0] + red[1] + red[2] + red[3];
      __syncthreads();
      float rstd = rsqrtf(sq * (1.f/512.f) + 1e-5f);
      a0 += d0*rstd*g[t]     + b[t];
      a1 += d1*rstd*g[t+256] + b[t+256];
    }
    feat[(size_t)n*512 + t]       = f2b(a0 * 0.25f);
    feat[(size_t)n*512 + t + 256] = f2b(a1 * 0.25f);
  } else {
    for (int i = (blockIdx.x - 2048)*256 + tid; i < 4718592; i += 4096*256){
      if (i < 524288) o1[i] = cvt4(w1[i]);
      else            o2[i - 524288] = cvt4(w2[i - 524288]);
    }
  }
}

// ---------------- causal dwconv (both dirs) + silu, 4 ch/thread ------------
__global__ __launch_bounds__(256) void dwconv2_kernel(
    const bf16* __restrict__ xz, const float* __restrict__ cw,
    const float* __restrict__ cb, bf16* __restrict__ u)
{
  const int n = blockIdx.x;
  const int c4 = threadIdx.x * 4;
  ushort4 in4[4];
  #pragma unroll
  for (int t = 0; t < 4; ++t)
    in4[t] = *reinterpret_cast<const ushort4*>(&xz[((size_t)n*4 + t)*2048 + c4]);
  #pragma unroll
  for (int d = 0; d < 2; ++d){
    const float* cwd = cw + d*4096;
    const float* cbd = cb + d*1024;
    ushort4 out[4];
    #pragma unroll
    for (int j = 0; j < 4; ++j){
      float xa[4];
      #pragma unroll
      for (int t = 0; t < 4; ++t){
        int ts = d ? 3 - t : t;
        unsigned short us = j==0?in4[ts].x : j==1?in4[ts].y : j==2?in4[ts].z : in4[ts].w;
        xa[t] = u2f(us);
      }
      float4 wv = *reinterpret_cast<const float4*>(&cwd[(c4 + j)*4]);
      float bb = cbd[c4 + j];
      float o[4];
      o[0] = xa[0]*wv.w + bb;
      o[1] = xa[0]*wv.z + xa[1]*wv.w + bb;
      o[2] = xa[0]*wv.y + xa[1]*wv.z + xa[2]*wv.w + bb;
      o[3] = xa[0]*wv.x + xa[1]*wv.y + xa[2]*wv.z + xa[3]*wv.w + bb;
      #pragma unroll
      for (int t = 0; t < 4; ++t){
        float v = o[t];
        float sv = v / (1.f + __expf(-v));
        unsigned short us = __bfloat16_as_ushort(f2b(sv));
        if (j==0) out[t].x = us; else if (j==1) out[t].y = us;
        else if (j==2) out[t].z = us; else out[t].w = us;
      }
    }
    #pragma unroll
    for (int t = 0; t < 4; ++t)
      *reinterpret_cast<ushort4*>(&u[(size_t)d*8388608 + ((size_t)n*4 + t)*1024 + c4]) = out[t];
  }
}

// ---------------- fused bidirectional scan + gate --------------------------
__global__ __launch_bounds__(256) void scan2_kernel(
    const float* __restrict__ dbl, const bf16* __restrict__ dt2,
    const bf16* __restrict__ u, const bf16* __restrict__ xz,
    const float* __restrict__ Atab2, const float* __restrict__ Dp,
    bf16* __restrict__ gated)
{
  __shared__ float Bs[2][4][16], Cs[2][4][16];
  const int n = blockIdx.x, g = blockIdx.y, tid = threadIdx.x;
  {
    int t = tid >> 6, j = tid & 63;
    int d = j >> 5, jj = j & 31;
    float v = dbl[((size_t)n*4 + t)*128 + d*64 + jj];
    if (jj < 16) Bs[d][t][jj] = v; else Cs[d][t][jj-16] = v;
  }
  __syncthreads();
  const int c = g*256 + tid;
  const size_t base = (size_t)n*4*1024 + c;
  float yo0[4], yo1[4];
  float hs[16];
  // ---- direction 0 ----
  {
    float A[16];
    const float4* ap = reinterpret_cast<const float4*>(Atab2 + (size_t)c*16);
    #pragma unroll
    for (int q = 0; q < 4; ++q){
      float4 v = ap[q];
      A[q*4+0]=v.x; A[q*4+1]=v.y; A[q*4+2]=v.z; A[q*4+3]=v.w;
    }
    const float Dpc = Dp[c];
    #pragma unroll
    for (int s = 0; s < 16; ++s) hs[s] = 0.f;
    #pragma unroll
    for (int t = 0; t < 4; ++t){
      float dtv = bfu(dt2[base + (size_t)t*1024]);
      float uv  = bfu(u  [base + (size_t)t*1024]);
      float du = dtv * uv;
      float yv = 0.f;
      #pragma unroll
      for (int s = 0; s < 16; ++s){
        float dA = __builtin_amdgcn_exp2f(dtv * A[s]);
        hs[s] = dA * hs[s] + du * Bs[0][t][s];
        yv += hs[s] * Cs[0][t][s];
      }
      yo0[t] = yv + uv * Dpc;
    }
  }
  // ---- direction 1 (time-reversed input; output flipped) ----
  {
    float A[16];
    const float4* ap = reinterpret_cast<const float4*>(Atab2 + 16384 + (size_t)c*16);
    #pragma unroll
    for (int q = 0; q < 4; ++q){
      float4 v = ap[q];
      A[q*4+0]=v.x; A[q*4+1]=v.y; A[q*4+2]=v.z; A[q*4+3]=v.w;
    }
    const float Dpc = Dp[1024 + c];
    #pragma unroll
    for (int s = 0; s < 16; ++s) hs[s] = 0.f;
    #pragma unroll
    for (int t = 0; t < 4; ++t){
      float dtv = bfu(dt2[8388608 + base + (size_t)t*1024]);
      float uv  = bfu(u  [8388608 + base + (size_t)t*1024]);
      float du = dtv * uv;
      float yv = 0.f;
      #pragma unroll
      for (int s = 0; s < 16; ++s){
        float dA = __builtin_amdgcn_exp2f(dtv * A[s]);
        hs[s] = dA * hs[s] + du * Bs[1][t][s];
        yv += hs[s] * Cs[1][t][s];
      }
      yo1[3 - t] = yv + uv * Dpc;
    }
  }
  // ---- gate + store (same thread wrote/read only channel c) ----
  #pragma unroll
  for (int t = 0; t < 4; ++t){
    float z = bfu(xz[(size_t)(n*4 + t)*2048 + 1024 + c]);
    float sv = z / (1.f + __expf(-z));
    gated[base + (size_t)t*1024] = f2b((yo0[t] + yo1[t]) * sv);
  }
}

// ---------------- launch ---------------------------------------------------
extern "C" void kernel_launch(void* const* d_in, const int* in_sizes, int n_in,
                              void* d_out, int out_size, void* d_ws, size_t ws_size,
                              hipStream_t stream)
{
  const float* x_flat    = (const float*)d_in[0];
  const float* conv_a_w  = (const float*)d_in[1];
  const float* conv_p_w  = (const float*)d_in[2];
  const float* se_w1     = (const float*)d_in[3];
  const float* se_b1     = (const float*)d_in[4];
  const float* se_w2     = (const float*)d_in[5];
  const float* se_b2     = (const float*)d_in[6];
  const float* ln_g      = (const float*)d_in[7];
  const float* ln_b      = (const float*)d_in[8];
  const float* in_proj_w = (const float*)d_in[9];
  const float* conv_w    = (const float*)d_in[10];
  const float* conv_b    = (const float*)d_in[11];
  const float* x_proj_w  = (const float*)d_in[12];
  const float* dt_proj_w = (const float*)d_in[13];
  const float* dt_proj_b = (const float*)d_in[14];
  const float* A_log     = (const float*)d_in[15];
  const float* D_param   = (const float*)d_in[16];
  const float* out_proj_w= (const float*)d_in[17];
  const float* out_ln_g  = (const float*)d_in[18];
  const float* out_ln_b  = (const float*)d_in[19];
  const float* mlp_w1    = (const float*)d_in[20];
  const float* mlp_b1    = (const float*)d_in[21];
  const float* mlp_w2    = (const float*)d_in[22];
  const float* mlp_b2    = (const float*)d_in[23];

  char* ws = (char*)d_ws;
  const size_t OFF_H    = 0;                       // f32  8192*512  = 16.78MB
  const size_t OFF_HN   = OFF_H    + 16777216;     // bf16 8192*512  (feat overlay)
  const size_t OFF_XZ   = OFF_HN   + 8388608;      // bf16 8192*2048 (z1 overlay)
  const size_t OFF_U    = OFF_XZ   + 33554432;     // bf16 u[2] 8192*1024
  const size_t OFF_SCR  = OFF_U    + 33554432;     // Aa(stem)/dbl+dtrb(layers)/wb1(MLP)
  const size_t OFF_YB   = OFF_SCR  + 25165824;     // Pm+wa+wp(stem)/dt2(layers)/wb2(MLP)
  const size_t OFF_WB   = OFF_YB   + 33554432;     // bf16 in_proj+out_proj
  const size_t OFF_WXP  = OFF_WB   + 6291456;      // bf16 packed x_proj
  const size_t OFF_WDT  = OFF_WXP  + 1048576;      // bf16 padded dt_proj
  const size_t OFF_ATAB = OFF_WDT  + 524288;       // f32  4*1024*16

  float* h    = (float*)(ws + OFF_H);
  bf16*  hn   = (bf16*) (ws + OFF_HN);
  bf16*  xz   = (bf16*) (ws + OFF_XZ);
  bf16*  u    = (bf16*) (ws + OFF_U);
  float* dbl  = (float*)(ws + OFF_SCR);
  bf16*  dtrb = (bf16*) (ws + OFF_SCR + 4194304);
  bf16*  dt2  = (bf16*) (ws + OFF_YB);
  bf16*  feat = (bf16*) (ws + OFF_HN);   // overlay
  bf16*  z1   = (bf16*) (ws + OFF_XZ);   // overlay
  bf16*  wbi  = (bf16*) (ws + OFF_WB);
  bf16*  wbo  = (bf16*) (ws + OFF_WB + 4194304);
  bf16*  wxp  = (bf16*) (ws + OFF_WXP);
  bf16*  wdtp = (bf16*) (ws + OFF_WDT);
  float* Atab = (float*)(ws + OFF_ATAB);
  bf16*  wb1  = (bf16*) (ws + OFF_SCR);  // overlay (MLP phase)
  bf16*  wb2  = (bf16*) (ws + OFF_YB);   // overlay (MLP phase)
  bf16*  Aa   = (bf16*) (ws + OFF_SCR);
  bf16*  Pm   = (bf16*) (ws + OFF_YB);
  bf16*  wa   = (bf16*) (ws + OFF_YB + 8388608);
  bf16*  wp   = (bf16*) (ws + OFF_YB + 8388608 + 786432);
  float* outf = (float*)d_out;

  prep_im2col_kernel<<<4096, 256, 0, stream>>>(
      x_flat, conv_a_w, conv_p_w, in_proj_w, out_proj_w, x_proj_w, dt_proj_w,
      A_log, Aa, Pm, wa, wp, wbi, wbo, wxp, wdtp, Atab);

  stemgemm_kernel<<<dim3(64,4), 256, 0, stream>>>(Aa, wa, Pm, wp, h);

  se_ln_kernel<<<2048, 256, 0, stream>>>(
      se_w1, se_b1, se_w2, se_b2, ln_g, ln_b, h, hn);

  for (int l = 0; l < 2; ++l){
    if (l == 1)
      ln_kernel<<<2048, 256, 0, stream>>>(h, ln_g + 512, ln_b + 512, hn);
    mgemm_kernel<0,0,false><<<dim3(64,16), 256, 0, stream>>>(
        hn, wbi + (size_t)l*2048*512, nullptr, xz, 512, 2048);
    dwconv2_kernel<<<2048, 256, 0, stream>>>(
        xz, conv_w + (size_t)l*8192, conv_b + (size_t)l*2048, u);
    bgemm_kernel<<<dim3(64,2), 256, 0, stream>>>(
        u, wxp + (size_t)l*262144, dtrb, dbl);
    dtgemm_kernel<<<dim3(128,8), 256, 0, stream>>>(
        dtrb, wdtp + (size_t)l*131072, dt_proj_b + (size_t)l*2048, dt2);
    scan2_kernel<<<dim3(2048,4), 256, 0, stream>>>(
        dbl, dt2, u, xz, Atab + (size_t)l*32768, D_param + (size_t)l*2048,
        u /* gated overlays u dir0 */);
    mgemm128_kernel<0,2,false><<<dim3(64,4), 256, 0, stream>>>(
        u, wbo + (size_t)l*512*1024, nullptr, h, 1024, 512);
  }

  finalln_mlp_kernel<<<6144, 256, 0, stream>>>(
      h, out_ln_g, out_ln_b, feat,
      (const float4*)mlp_w1, (const float4*)mlp_w2, (ushort4*)wb1, (ushort4*)wb2);

  mgemm128_kernel<1,0,true><<<dim3(16,32), 256, 0, stream>>>(
      feat, wb1, mlp_b1, z1, 512, 4096);
  mgemm128_kernel<1,1,true><<<dim3(16,32), 256, 0, stream>>>(
      z1, wb2, mlp_b2, outf, 4096, 4096);
}